// Round 4
// baseline (6026.083 us; speedup 1.0000x reference)
//
#include <hip/hip_runtime.h>
#include <hip/hip_bf16.h>
#include <math.h>

// Problem constants (B=2, S=2048, D=1024, H=16, DH=64, FF=4096)
#define BB 2
#define SS 2048
#define DD 1024
#define HH 16
#define DHD 64
#define FFD 4096
#define NROWS (BB*SS)

typedef __bf16 bf16_t;
typedef __bf16 bf16x8 __attribute__((ext_vector_type(8)));
typedef float floatx4 __attribute__((ext_vector_type(4)));

union FragU { uint4 u; bf16x8 v; bf16_t e[8]; };

static __device__ __forceinline__ bf16x8 ld_frag16(const bf16_t* p) {
  FragU f; f.u = *reinterpret_cast<const uint4*>(p); return f.v;
}

// ---------------------------------------------------------------------------
// Detector: flags[0]=1 if float tensors are really f32 (read-as-bf16 shows huge
// exponents); flags[1]=1 if masks are byte-packed (int32 words not in {0,1}).
// One block, 256 threads.
// ---------------------------------------------------------------------------
__global__ __launch_bounds__(256) void detect_k(const void* __restrict__ xp,
                                                const void* __restrict__ ep,
                                                const void* __restrict__ wp,
                                                const int* __restrict__ mk,
                                                int* __restrict__ flags) {
  const int t = threadIdx.x;
  const unsigned short* a = (const unsigned short*)xp;
  const unsigned short* b = (const unsigned short*)ep;
  const unsigned short* c = (const unsigned short*)wp;
  int bad = 0, mbad = 0;
  for (int i = t; i < 4096; i += 256) {
    int e1 = (a[i] >> 7) & 0xFF, e2 = (b[i] >> 7) & 0xFF, e3 = (c[i] >> 7) & 0xFF;
    // sane bf16 data here is |v| < 1e3 (exp < 0x89); f32-garbage low halves are
    // near-uniform u16 -> ~40% have exp >= 0x9B (|v| >= 2^28) incl. Inf/NaN.
    if (e1 >= 0x9B || e2 >= 0x9B || e3 >= 0x9B) bad = 1;
  }
  for (int i = t; i < 1024; i += 256) {      // 4KB: in-bounds for int8 or int32 masks
    unsigned v = (unsigned)mk[i];
    if (v > 1u) mbad = 1;
  }
  __shared__ int s0, s1;
  if (t == 0) { s0 = 0; s1 = 0; }
  __syncthreads();
  if (bad)  atomicOr(&s0, 1);
  if (mbad) atomicOr(&s1, 1);
  __syncthreads();
  if (t == 0) { flags[0] = s0; flags[1] = s1; }
}

// ---------------------------------------------------------------------------
// Canonicalize a float tensor to bf16 (copy if already bf16).
// ---------------------------------------------------------------------------
__global__ __launch_bounds__(256) void cvt_k(const void* __restrict__ src,
                                             bf16_t* __restrict__ dst, int n,
                                             const int* __restrict__ flg) {
  const int f32m = flg[0];
  const int idx = blockIdx.x * 256 + threadIdx.x;
  const int stride = gridDim.x * 256;
  if (f32m) {
    const float* s = (const float*)src;
    for (int i = idx; i < n; i += stride) dst[i] = (bf16_t)s[i];
  } else {
    const bf16_t* s = (const bf16_t*)src;
    for (int i = idx; i < n; i += stride) dst[i] = s[i];
  }
}

// ---------------------------------------------------------------------------
// Transpose raw weight (f32 or bf16 per flag) -> bf16 out[c][r].
// rows,cols multiples of 64.  grid (cols/64, rows/64), block 256.
// ---------------------------------------------------------------------------
__global__ __launch_bounds__(256) void transpose_k(const void* __restrict__ inv,
                                                   bf16_t* __restrict__ out,
                                                   int rows, int cols,
                                                   const int* __restrict__ flg) {
  __shared__ __align__(16) bf16_t tile[64][72];
  const int f32m = flg[0];
  const int c0 = blockIdx.x * 64, r0 = blockIdx.y * 64;
  const int t  = threadIdx.x;
  const int lr = t >> 3;            // 0..31
  const int lc = (t & 7) * 8;       // 0..56
#pragma unroll
  for (int half = 0; half < 2; ++half) {
    int r = lr + half * 32;
    if (f32m) {
      const float* p = (const float*)inv + (size_t)(r0 + r) * cols + c0 + lc;
      float4 q0 = *reinterpret_cast<const float4*>(p);
      float4 q1 = *reinterpret_cast<const float4*>(p + 4);
      tile[r][lc+0] = (bf16_t)q0.x; tile[r][lc+1] = (bf16_t)q0.y;
      tile[r][lc+2] = (bf16_t)q0.z; tile[r][lc+3] = (bf16_t)q0.w;
      tile[r][lc+4] = (bf16_t)q1.x; tile[r][lc+5] = (bf16_t)q1.y;
      tile[r][lc+6] = (bf16_t)q1.z; tile[r][lc+7] = (bf16_t)q1.w;
    } else {
      uint4 vv = *reinterpret_cast<const uint4*>((const bf16_t*)inv + (size_t)(r0 + r) * cols + c0 + lc);
      *reinterpret_cast<uint4*>(&tile[r][lc]) = vv;
    }
  }
  __syncthreads();
#pragma unroll
  for (int half = 0; half < 2; ++half) {
    int oc = lr + half * 32;
    FragU f;
#pragma unroll
    for (int j = 0; j < 8; ++j) f.e[j] = tile[lc + j][oc];
    *reinterpret_cast<uint4*>(out + (size_t)(c0 + oc) * rows + r0 + lc) = f.u;
  }
}

// ---------------------------------------------------------------------------
// GEMM: C[M,N] = A[M,K] @ Bt[N,K]^T (+bias, +exact GELU).  All bf16 canonical.
// Block tile 64(M) x 128(N), BK=32, 256 threads = 4 waves.  grid (N/128, M/64).
// ---------------------------------------------------------------------------
template<int BIAS, int GELU>
__global__ __launch_bounds__(256) void gemm_nt(const bf16_t* __restrict__ A,
                                               const bf16_t* __restrict__ Bt,
                                               const bf16_t* __restrict__ bias,
                                               bf16_t* __restrict__ C,
                                               int M, int N, int K) {
  __shared__ __align__(16) bf16_t As[64][40];
  __shared__ __align__(16) bf16_t Bs[128][40];
  const int m0 = blockIdx.y * 64, n0 = blockIdx.x * 128;
  const int t = threadIdx.x;
  const int lane = t & 63, w = t >> 6;
  const int quad = lane >> 4, l16 = lane & 15;
  const int wn = w * 32;

  floatx4 acc[4][2];
#pragma unroll
  for (int i = 0; i < 4; ++i)
#pragma unroll
    for (int j = 0; j < 2; ++j) { floatx4 z = {0.f,0.f,0.f,0.f}; acc[i][j] = z; }

  const int row0 = t >> 2;
  const int cc0  = (t & 3) * 8;

  for (int k0 = 0; k0 < K; k0 += 32) {
    __syncthreads();
    uint4 a0 = *reinterpret_cast<const uint4*>(A  + (size_t)(m0 + row0)      * K + k0 + cc0);
    uint4 b0 = *reinterpret_cast<const uint4*>(Bt + (size_t)(n0 + row0)      * K + k0 + cc0);
    uint4 b1 = *reinterpret_cast<const uint4*>(Bt + (size_t)(n0 + row0 + 64) * K + k0 + cc0);
    *reinterpret_cast<uint4*>(&As[row0][cc0])      = a0;
    *reinterpret_cast<uint4*>(&Bs[row0][cc0])      = b0;
    *reinterpret_cast<uint4*>(&Bs[row0 + 64][cc0]) = b1;
    __syncthreads();

    bf16x8 af[4], bfr[2];
#pragma unroll
    for (int mt = 0; mt < 4; ++mt) af[mt]  = ld_frag16(&As[mt*16 + l16][quad*8]);
#pragma unroll
    for (int nt = 0; nt < 2; ++nt) bfr[nt] = ld_frag16(&Bs[wn + nt*16 + l16][quad*8]);
#pragma unroll
    for (int mt = 0; mt < 4; ++mt)
#pragma unroll
      for (int nt = 0; nt < 2; ++nt)
        acc[mt][nt] = __builtin_amdgcn_mfma_f32_16x16x32_bf16(af[mt], bfr[nt], acc[mt][nt], 0, 0, 0);
  }

#pragma unroll
  for (int nt = 0; nt < 2; ++nt) {
    const int c = n0 + wn + nt*16 + l16;
    float bv = 0.f;
    if (BIAS) bv = (float)bias[c];
#pragma unroll
    for (int mt = 0; mt < 4; ++mt) {
      const int rb = m0 + mt*16 + quad*4;
#pragma unroll
      for (int reg = 0; reg < 4; ++reg) {
        float v2 = acc[mt][nt][reg] + bv;
        if (GELU) v2 = 0.5f * v2 * (1.f + erff(v2 * 0.70710678118654752f));
        C[(size_t)(rb + reg) * N + c] = (bf16_t)v2;
      }
    }
  }
}

// ---------------------------------------------------------------------------
// Naive attention (correctness-first).  One block per (query i, b, h).
// grid (S, B*H), block 256.  Mask read width per flags[1].
// ---------------------------------------------------------------------------
__global__ __launch_bounds__(256) void attn_naive(const bf16_t* __restrict__ Q,
                                                  const bf16_t* __restrict__ Kb,
                                                  const bf16_t* __restrict__ Vb,
                                                  const int* __restrict__ mask,
                                                  bf16_t* __restrict__ O,
                                                  const int* __restrict__ flg) {
  __shared__ float sc[SS];
  __shared__ float qrow[DHD];
  __shared__ float red[8];
  __shared__ float ored[4][DHD];
  const int mflag = flg[1];
  const int b = blockIdx.y >> 4, h = blockIdx.y & 15;
  const int i = blockIdx.x;
  const int t = threadIdx.x;
  const float NEG = -1.0e30f;
  const size_t rowQ = (size_t)(b * SS + i) * DD + h * DHD;

  if (t < DHD) qrow[t] = (float)Q[rowQ + t];
  __syncthreads();

  for (int j = t; j < SS; j += 256) {
    const bf16_t* kp = Kb + (size_t)(b * SS + j) * DD + h * DHD;
    float acc = 0.f;
#pragma unroll
    for (int c = 0; c < 8; ++c) {
      FragU f; f.u = *reinterpret_cast<const uint4*>(kp + c * 8);
#pragma unroll
      for (int e = 0; e < 8; ++e) acc += qrow[c * 8 + e] * (float)f.e[e];
    }
    const int mi = b * SS + j;
    const int mv = mflag ? (int)((const signed char*)mask)[mi] : mask[mi];
    sc[j] = mv ? NEG : acc * 0.125f;
  }
  __syncthreads();

  float m = NEG;
  for (int j = t; j < SS; j += 256) m = fmaxf(m, sc[j]);
#pragma unroll
  for (int off = 1; off < 64; off <<= 1) m = fmaxf(m, __shfl_xor(m, off, 64));
  if ((t & 63) == 0) red[t >> 6] = m;
  __syncthreads();
  m = fmaxf(fmaxf(red[0], red[1]), fmaxf(red[2], red[3]));

  float ls = 0.f;
  for (int j = t; j < SS; j += 256) { float p = __expf(sc[j] - m); sc[j] = p; ls += p; }
#pragma unroll
  for (int off = 1; off < 64; off <<= 1) ls += __shfl_xor(ls, off, 64);
  if ((t & 63) == 0) red[4 + (t >> 6)] = ls;
  __syncthreads();
  ls = red[4] + red[5] + red[6] + red[7];

  const int d = t & 63, jq = t >> 6;
  const bf16_t* vp = Vb + (size_t)(b * SS + jq * 512) * DD + h * DHD + d;
  float o = 0.f;
  for (int j = 0; j < 512; ++j) o += sc[jq * 512 + j] * (float)vp[(size_t)j * DD];
  ored[jq][d] = o;
  __syncthreads();
  if (t < DHD) {
    float oo = ored[0][t] + ored[1][t] + ored[2][t] + ored[3][t];
    O[rowQ + t] = (bf16_t)(oo / ls);
  }
}

// ---------------------------------------------------------------------------
// y = LayerNorm(x + a) * g + b.  One block per row.  Alias-safe (Y==X ok).
// final_out!=0: write f32 if flags[0] says the problem runs in f32.
// ---------------------------------------------------------------------------
__global__ __launch_bounds__(256) void ln_add_k(const bf16_t* __restrict__ X,
                                                const bf16_t* __restrict__ A,
                                                const bf16_t* __restrict__ g,
                                                const bf16_t* __restrict__ bb,
                                                void* __restrict__ Yv,
                                                const int* __restrict__ flg,
                                                int final_out) {
  const int row = blockIdx.x;
  const int t = threadIdx.x;
  const int f32o = final_out ? flg[0] : 0;
  const bf16_t* xp = X + (size_t)row * DD;
  const bf16_t* ap = A + (size_t)row * DD;
  float v[4], s = 0.f, sq = 0.f;
#pragma unroll
  for (int i = 0; i < 4; ++i) {
    float xv = (float)xp[t + i * 256] + (float)ap[t + i * 256];
    v[i] = xv; s += xv; sq += xv * xv;
  }
#pragma unroll
  for (int off = 1; off < 64; off <<= 1) {
    s  += __shfl_xor(s, off, 64);
    sq += __shfl_xor(sq, off, 64);
  }
  __shared__ float red[2][4];
  const int w = t >> 6, lane = t & 63;
  if (lane == 0) { red[0][w] = s; red[1][w] = sq; }
  __syncthreads();
  s  = red[0][0] + red[0][1] + red[0][2] + red[0][3];
  sq = red[1][0] + red[1][1] + red[1][2] + red[1][3];
  const float mean = s * (1.f / 1024.f);
  const float var  = sq * (1.f / 1024.f) - mean * mean;
  const float rstd = rsqrtf(var + 1e-5f);
#pragma unroll
  for (int i = 0; i < 4; ++i) {
    const int c = t + i * 256;
    const float val = (v[i] - mean) * rstd * (float)g[c] + (float)bb[c];
    if (f32o) ((float*)Yv)[(size_t)row * DD + c] = val;
    else      ((bf16_t*)Yv)[(size_t)row * DD + c] = (bf16_t)val;
  }
}

// ---------------------------------------------------------------------------
// Beacon: encode a diagnostic constant into the output.
// ---------------------------------------------------------------------------
__global__ __launch_bounds__(256) void beacon_k(bf16_t* out, int n, float val) {
  int i = blockIdx.x * 256 + threadIdx.x;
  if (i < n) out[i] = (bf16_t)val;
}

// ---------------------------------------------------------------------------
extern "C" void kernel_launch(void* const* d_in, const int* in_sizes, int n_in,
                              void* d_out, int out_size, void* d_ws, size_t ws_size,
                              hipStream_t stream) {
  const dim3 blk(256);
  const dim3 gB((out_size + 255) / 256);

  // ---- input-signature validation (element counts per setup_inputs order) ----
  static const int expect[24] = {
    4194304, 4194304,                              // x, enc
    1048576, 1048576, 1048576, 1048576, 1024,      // sa_wq..sa_wo, sa_bo
    1048576, 1048576, 1048576, 1048576, 1024,      // ca_wq..ca_wo, ca_bo
    1024, 1024, 1024, 1024, 1024, 1024,            // ln1..ln3 g/b
    4194304, 4096,                                 // fc1_w, fc1_b
    4194304, 1024,                                 // fc2_w, fc2_b
    4096, 4096                                     // tgt_mask, src_mask
  };
  if (n_in != 24) {
    beacon_k<<<gB, blk, 0, stream>>>((bf16_t*)d_out, out_size, 200.f + (float)(n_in & 63));
    return;
  }
  for (int i = 0; i < 24; ++i) {
    if (in_sizes[i] != expect[i]) {
      beacon_k<<<gB, blk, 0, stream>>>((bf16_t*)d_out, out_size, 20.f + 2.f * (float)i);
      return;
    }
  }

  const void* x_raw   = d_in[0];
  const void* enc_raw = d_in[1];
  const void* sa_wq = d_in[2], *sa_wk = d_in[3], *sa_wv = d_in[4], *sa_wo = d_in[5];
  const void* sa_bo = d_in[6];
  const void* ca_wq = d_in[7], *ca_wk = d_in[8], *ca_wv = d_in[9], *ca_wo = d_in[10];
  const void* ca_bo = d_in[11];
  const void* ln1_g = d_in[12], *ln1_b = d_in[13];
  const void* ln2_g = d_in[14], *ln2_b = d_in[15];
  const void* ln3_g = d_in[16], *ln3_b = d_in[17];
  const void* fc1_w = d_in[18], *fc1_b = d_in[19];
  const void* fc2_w = d_in[20], *fc2_b = d_in[21];
  const int* tgt_mask = (const int*)d_in[22];
  const int* src_mask = (const int*)d_in[23];

  // ---- workspace layout ----
  const size_t SEG = (size_t)NROWS * DD;           // 4,194,304 elems = 8 MiB bf16
  const size_t PS_ELEMS = 32768;                   // params + flags area (64 KiB)
  if (ws_size < (8 * SEG + PS_ELEMS) * sizeof(bf16_t)) {
    beacon_k<<<gB, blk, 0, stream>>>((bf16_t*)d_out, out_size, 7.f);   // ws too small
    return;
  }
  bf16_t* ws = (bf16_t*)d_ws;
  bf16_t* qb = ws + 0 * SEG;        // q / attn-out t0
  bf16_t* kb = ws + 1 * SEG;
  bf16_t* vb = ws + 2 * SEG;        // v / MLP h-chunk (chunked path)
  bf16_t* wt = ws + 3 * SEG;        // current transposed weight
  bf16_t* t1 = ws + 4 * SEG;
  bf16_t* x1 = ws + 5 * SEG;        // ln1 out; ln2 in-place out (x2)
  bf16_t* xc = ws + 6 * SEG;        // canonical bf16 x
  bf16_t* ec = ws + 7 * SEG;        // canonical bf16 enc
  bf16_t* ps = ws + 8 * SEG;        // canonical small params
  int*    fl = (int*)(ps + 16384);  // flags[0]=f32 inputs, flags[1]=int8 masks
  bf16_t* t0 = qb;
  bf16_t* x2 = x1;                  // in-place ln2 (alias-safe per-row)
  const bool big_ws = ws_size >= (12 * SEG + PS_ELEMS) * sizeof(bf16_t);
  bf16_t* hb = ws + 8 * SEG + PS_ELEMS;  // [4096][4096] hidden (big path only)

  // canonical param slots
  bf16_t* c_ln1g = ps + 0,    *c_ln1b = ps + 1024;
  bf16_t* c_ln2g = ps + 2048, *c_ln2b = ps + 3072;
  bf16_t* c_ln3g = ps + 4096, *c_ln3b = ps + 5120;
  bf16_t* c_sabo = ps + 6144, *c_cabo = ps + 7168;
  bf16_t* c_f1b  = ps + 8192;                      // 4096
  bf16_t* c_f2b  = ps + 12288;                     // 1024

  const dim3 gT(16, 16);
  const dim3 gG(DD / 128, NROWS / 64);
  const dim3 gA(SS, BB * HH);
  const dim3 gL(NROWS);
  const dim3 gC(512);

  // ---- detect dtypes, canonicalize ----
  detect_k<<<dim3(1), blk, 0, stream>>>(x_raw, enc_raw, fc1_w, tgt_mask, fl);
  cvt_k<<<gC, blk, 0, stream>>>(x_raw,   xc, (int)SEG, fl);
  cvt_k<<<gC, blk, 0, stream>>>(enc_raw, ec, (int)SEG, fl);
  cvt_k<<<dim3(4), blk, 0, stream>>>(ln1_g, c_ln1g, 1024, fl);
  cvt_k<<<dim3(4), blk, 0, stream>>>(ln1_b, c_ln1b, 1024, fl);
  cvt_k<<<dim3(4), blk, 0, stream>>>(ln2_g, c_ln2g, 1024, fl);
  cvt_k<<<dim3(4), blk, 0, stream>>>(ln2_b, c_ln2b, 1024, fl);
  cvt_k<<<dim3(4), blk, 0, stream>>>(ln3_g, c_ln3g, 1024, fl);
  cvt_k<<<dim3(4), blk, 0, stream>>>(ln3_b, c_ln3b, 1024, fl);
  cvt_k<<<dim3(4), blk, 0, stream>>>(sa_bo, c_sabo, 1024, fl);
  cvt_k<<<dim3(4), blk, 0, stream>>>(ca_bo, c_cabo, 1024, fl);
  cvt_k<<<dim3(16), blk, 0, stream>>>(fc1_b, c_f1b, 4096, fl);
  cvt_k<<<dim3(4), blk, 0, stream>>>(fc2_b, c_f2b, 1024, fl);

  // ---- self attention ----
  transpose_k<<<gT, blk, 0, stream>>>(sa_wq, wt, DD, DD, fl);
  gemm_nt<0,0><<<gG, blk, 0, stream>>>(xc, wt, nullptr, qb, NROWS, DD, DD);
  transpose_k<<<gT, blk, 0, stream>>>(sa_wk, wt, DD, DD, fl);
  gemm_nt<0,0><<<gG, blk, 0, stream>>>(xc, wt, nullptr, kb, NROWS, DD, DD);
  transpose_k<<<gT, blk, 0, stream>>>(sa_wv, wt, DD, DD, fl);
  gemm_nt<0,0><<<gG, blk, 0, stream>>>(xc, wt, nullptr, vb, NROWS, DD, DD);
  attn_naive<<<gA, blk, 0, stream>>>(qb, kb, vb, tgt_mask, t0, fl);
  transpose_k<<<gT, blk, 0, stream>>>(sa_wo, wt, DD, DD, fl);
  gemm_nt<1,0><<<gG, blk, 0, stream>>>(t0, wt, c_sabo, t1, NROWS, DD, DD);
  ln_add_k<<<gL, blk, 0, stream>>>(xc, t1, c_ln1g, c_ln1b, x1, fl, 0);

  // ---- cross attention ----
  transpose_k<<<gT, blk, 0, stream>>>(ca_wq, wt, DD, DD, fl);
  gemm_nt<0,0><<<gG, blk, 0, stream>>>(x1, wt, nullptr, qb, NROWS, DD, DD);
  transpose_k<<<gT, blk, 0, stream>>>(ca_wk, wt, DD, DD, fl);
  gemm_nt<0,0><<<gG, blk, 0, stream>>>(ec, wt, nullptr, kb, NROWS, DD, DD);
  transpose_k<<<gT, blk, 0, stream>>>(ca_wv, wt, DD, DD, fl);
  gemm_nt<0,0><<<gG, blk, 0, stream>>>(ec, wt, nullptr, vb, NROWS, DD, DD);
  attn_naive<<<gA, blk, 0, stream>>>(qb, kb, vb, src_mask, t0, fl);
  transpose_k<<<gT, blk, 0, stream>>>(ca_wo, wt, DD, DD, fl);
  gemm_nt<1,0><<<gG, blk, 0, stream>>>(t0, wt, c_cabo, t1, NROWS, DD, DD);
  ln_add_k<<<gL, blk, 0, stream>>>(x1, t1, c_ln2g, c_ln2b, x2, fl, 0);   // x2 == x1 in-place

  // ---- MLP ----
  transpose_k<<<dim3(FFD/64, DD/64), blk, 0, stream>>>(fc1_w, wt, DD, FFD, fl);  // fc1^T [FF][D]
  if (big_ws) {
    gemm_nt<1,1><<<dim3(FFD/128, NROWS/64), blk, 0, stream>>>(x2, wt, c_f1b, hb, NROWS, FFD, DD);
    transpose_k<<<dim3(DD/64, FFD/64), blk, 0, stream>>>(fc2_w, wt, FFD, DD, fl); // fc2^T [D][FF]
    gemm_nt<1,0><<<dim3(DD/128,  NROWS/64), blk, 0, stream>>>(hb, wt, c_f2b, t1, NROWS, DD, FFD);
  } else {
    transpose_k<<<dim3(DD/64, FFD/64), blk, 0, stream>>>(fc2_w, kb, FFD, DD, fl); // fc2^T in kb
    for (int c = 0; c < 4; ++c) {   // 1024-row chunks; hidden chunk in vb
      gemm_nt<1,1><<<dim3(FFD/128, 16), blk, 0, stream>>>(x2 + (size_t)c*1024*DD, wt, c_f1b, vb, 1024, FFD, DD);
      gemm_nt<1,0><<<dim3(DD/128,  16), blk, 0, stream>>>(vb, kb, c_f2b, t1 + (size_t)c*1024*DD, 1024, DD, FFD);
    }
  }
  ln_add_k<<<gL, blk, 0, stream>>>(x2, t1, c_ln3g, c_ln3b, d_out, fl, 1);
}

// Round 5
// 1056.751 us; speedup vs baseline: 5.7025x; 5.7025x over previous
//
#include <hip/hip_runtime.h>
#include <hip/hip_bf16.h>
#include <math.h>

// Problem constants (B=2, S=2048, D=1024, H=16, DH=64, FF=4096)
#define BB 2
#define SS 2048
#define DD 1024
#define HH 16
#define DHD 64
#define FFD 4096
#define NROWS (BB*SS)

typedef __bf16 bf16_t;
typedef __bf16 bf16x8 __attribute__((ext_vector_type(8)));
typedef float floatx4 __attribute__((ext_vector_type(4)));

union FragU { uint4 u; bf16x8 v; bf16_t e[8]; };

static __device__ __forceinline__ bf16x8 ld_frag16(const bf16_t* p) {
  FragU f; f.u = *reinterpret_cast<const uint4*>(p); return f.v;
}

// ---------------------------------------------------------------------------
// Detector: flags[0]=1 if float tensors are really f32 (read-as-bf16 shows huge
// exponents); flags[1]=1 if masks are byte-packed (int32 words not in {0,1}).
// ---------------------------------------------------------------------------
__global__ __launch_bounds__(256) void detect_k(const void* __restrict__ xp,
                                                const void* __restrict__ ep,
                                                const void* __restrict__ wp,
                                                const int* __restrict__ mk,
                                                int* __restrict__ flags) {
  const int t = threadIdx.x;
  const unsigned short* a = (const unsigned short*)xp;
  const unsigned short* b = (const unsigned short*)ep;
  const unsigned short* c = (const unsigned short*)wp;
  int bad = 0, mbad = 0;
  for (int i = t; i < 4096; i += 256) {
    int e1 = (a[i] >> 7) & 0xFF, e2 = (b[i] >> 7) & 0xFF, e3 = (c[i] >> 7) & 0xFF;
    if (e1 >= 0x9B || e2 >= 0x9B || e3 >= 0x9B) bad = 1;
  }
  for (int i = t; i < 1024; i += 256) {
    unsigned v = (unsigned)mk[i];
    if (v > 1u) mbad = 1;
  }
  __shared__ int s0, s1;
  if (t == 0) { s0 = 0; s1 = 0; }
  __syncthreads();
  if (bad)  atomicOr(&s0, 1);
  if (mbad) atomicOr(&s1, 1);
  __syncthreads();
  if (t == 0) { flags[0] = s0; flags[1] = s1; }
}

// ---------------------------------------------------------------------------
// Canonicalize a float tensor to bf16 (copy if already bf16).
// ---------------------------------------------------------------------------
__global__ __launch_bounds__(256) void cvt_k(const void* __restrict__ src,
                                             bf16_t* __restrict__ dst, int n,
                                             const int* __restrict__ flg) {
  const int f32m = flg[0];
  const int idx = blockIdx.x * 256 + threadIdx.x;
  const int stride = gridDim.x * 256;
  if (f32m) {
    const float* s = (const float*)src;
    for (int i = idx; i < n; i += stride) dst[i] = (bf16_t)s[i];
  } else {
    const bf16_t* s = (const bf16_t*)src;
    for (int i = idx; i < n; i += stride) dst[i] = s[i];
  }
}

// ---------------------------------------------------------------------------
// Transpose raw weight (f32 or bf16 per flag) -> bf16 out[c][r].
// rows,cols multiples of 64.  grid (cols/64, rows/64), block 256.
// ---------------------------------------------------------------------------
__global__ __launch_bounds__(256) void transpose_k(const void* __restrict__ inv,
                                                   bf16_t* __restrict__ out,
                                                   int rows, int cols,
                                                   const int* __restrict__ flg) {
  __shared__ __align__(16) bf16_t tile[64][72];
  const int f32m = flg[0];
  const int c0 = blockIdx.x * 64, r0 = blockIdx.y * 64;
  const int t  = threadIdx.x;
  const int lr = t >> 3;            // 0..31
  const int lc = (t & 7) * 8;       // 0..56
#pragma unroll
  for (int half = 0; half < 2; ++half) {
    int r = lr + half * 32;
    if (f32m) {
      const float* p = (const float*)inv + (size_t)(r0 + r) * cols + c0 + lc;
      float4 q0 = *reinterpret_cast<const float4*>(p);
      float4 q1 = *reinterpret_cast<const float4*>(p + 4);
      tile[r][lc+0] = (bf16_t)q0.x; tile[r][lc+1] = (bf16_t)q0.y;
      tile[r][lc+2] = (bf16_t)q0.z; tile[r][lc+3] = (bf16_t)q0.w;
      tile[r][lc+4] = (bf16_t)q1.x; tile[r][lc+5] = (bf16_t)q1.y;
      tile[r][lc+6] = (bf16_t)q1.z; tile[r][lc+7] = (bf16_t)q1.w;
    } else {
      uint4 vv = *reinterpret_cast<const uint4*>((const bf16_t*)inv + (size_t)(r0 + r) * cols + c0 + lc);
      *reinterpret_cast<uint4*>(&tile[r][lc]) = vv;
    }
  }
  __syncthreads();
#pragma unroll
  for (int half = 0; half < 2; ++half) {
    int oc = lr + half * 32;
    FragU f;
#pragma unroll
    for (int j = 0; j < 8; ++j) f.e[j] = tile[lc + j][oc];
    *reinterpret_cast<uint4*>(out + (size_t)(c0 + oc) * rows + r0 + lc) = f.u;
  }
}

// ---------------------------------------------------------------------------
// GEMM: C[M,N] = A[M,K] @ Bt[N,K]^T (+bias, +exact GELU).  All bf16 canonical.
// Block tile 64(M) x 128(N), BK=32, 256 threads = 4 waves.  grid (N/128, M/64).
// ---------------------------------------------------------------------------
template<int BIAS, int GELU>
__global__ __launch_bounds__(256) void gemm_nt(const bf16_t* __restrict__ A,
                                               const bf16_t* __restrict__ Bt,
                                               const bf16_t* __restrict__ bias,
                                               bf16_t* __restrict__ C,
                                               int M, int N, int K) {
  __shared__ __align__(16) bf16_t As[64][40];
  __shared__ __align__(16) bf16_t Bs[128][40];
  const int m0 = blockIdx.y * 64, n0 = blockIdx.x * 128;
  const int t = threadIdx.x;
  const int lane = t & 63, w = t >> 6;
  const int quad = lane >> 4, l16 = lane & 15;
  const int wn = w * 32;

  floatx4 acc[4][2];
#pragma unroll
  for (int i = 0; i < 4; ++i)
#pragma unroll
    for (int j = 0; j < 2; ++j) { floatx4 z = {0.f,0.f,0.f,0.f}; acc[i][j] = z; }

  const int row0 = t >> 2;
  const int cc0  = (t & 3) * 8;

  for (int k0 = 0; k0 < K; k0 += 32) {
    __syncthreads();
    uint4 a0 = *reinterpret_cast<const uint4*>(A  + (size_t)(m0 + row0)      * K + k0 + cc0);
    uint4 b0 = *reinterpret_cast<const uint4*>(Bt + (size_t)(n0 + row0)      * K + k0 + cc0);
    uint4 b1 = *reinterpret_cast<const uint4*>(Bt + (size_t)(n0 + row0 + 64) * K + k0 + cc0);
    *reinterpret_cast<uint4*>(&As[row0][cc0])      = a0;
    *reinterpret_cast<uint4*>(&Bs[row0][cc0])      = b0;
    *reinterpret_cast<uint4*>(&Bs[row0 + 64][cc0]) = b1;
    __syncthreads();

    bf16x8 af[4], bfr[2];
#pragma unroll
    for (int mt = 0; mt < 4; ++mt) af[mt]  = ld_frag16(&As[mt*16 + l16][quad*8]);
#pragma unroll
    for (int nt = 0; nt < 2; ++nt) bfr[nt] = ld_frag16(&Bs[wn + nt*16 + l16][quad*8]);
#pragma unroll
    for (int mt = 0; mt < 4; ++mt)
#pragma unroll
      for (int nt = 0; nt < 2; ++nt)
        acc[mt][nt] = __builtin_amdgcn_mfma_f32_16x16x32_bf16(af[mt], bfr[nt], acc[mt][nt], 0, 0, 0);
  }

#pragma unroll
  for (int nt = 0; nt < 2; ++nt) {
    const int c = n0 + wn + nt*16 + l16;
    float bv = 0.f;
    if (BIAS) bv = (float)bias[c];
#pragma unroll
    for (int mt = 0; mt < 4; ++mt) {
      const int rb = m0 + mt*16 + quad*4;
#pragma unroll
      for (int reg = 0; reg < 4; ++reg) {
        float v2 = acc[mt][nt][reg] + bv;
        if (GELU) v2 = 0.5f * v2 * (1.f + erff(v2 * 0.70710678118654752f));
        C[(size_t)(rb + reg) * N + c] = (bf16_t)v2;
      }
    }
  }
}

// ---------------------------------------------------------------------------
// MFMA flash attention.  Q,K,V: [B*S, 1024] bf16, head h = cols h*64..h*64+63.
// mask[b][j] nonzero => key j masked.  Mask width per flags[1].
// grid (S/64, B*H), block 256 (4 waves, wave = 16 q-rows).  32-key tiles.
// ---------------------------------------------------------------------------
__global__ __launch_bounds__(256) void attn_k(const bf16_t* __restrict__ Q,
                                              const bf16_t* __restrict__ Kb,
                                              const bf16_t* __restrict__ Vb,
                                              const int* __restrict__ mask,
                                              bf16_t* __restrict__ O,
                                              const int* __restrict__ flg) {
  __shared__ __align__(16) bf16_t Ks[32][72];     // [key][dh]
  __shared__ __align__(16) bf16_t Vt[64][40];     // [dh][key]
  __shared__ __align__(16) bf16_t Ps[4][16][40];  // per-wave P: [qrow][key]
  const int mflag = flg[1];
  const int bh = blockIdx.y;
  const int b = bh >> 4, h = bh & 15;
  const int s0 = blockIdx.x * 64;
  const int t = threadIdx.x, w = t >> 6, lane = t & 63;
  const int quad = lane >> 4, l16 = lane & 15;
  const float NEG = -1.0e30f;
  const float SCALE = 0.125f;       // 64^-0.5

  // Q A-fragments (m = l16, k = quad*8+j), 2 K=32 steps over DH=64
  bf16x8 qf[2];
  {
    const int r = s0 + w * 16 + l16;
    const bf16_t* qp = Q + (size_t)(b * SS + r) * DD + h * DHD;
#pragma unroll
    for (int ks = 0; ks < 2; ++ks) qf[ks] = ld_frag16(qp + ks * 32 + quad * 8);
  }

  float m_i[4], l_i[4];
  floatx4 accO[4];
#pragma unroll
  for (int i = 0; i < 4; ++i) {
    m_i[i] = NEG; l_i[i] = 0.f;
    floatx4 z = {0.f,0.f,0.f,0.f}; accO[i] = z;
  }

  const int key = t >> 3;           // 0..31 staging row
  const int c8  = (t & 7) * 8;      // 0..56 staging col

  for (int j0 = 0; j0 < SS; j0 += 32) {
    __syncthreads();                // prev-iter Vt/Ks reads done before restage
    {
      const bf16_t* kp = Kb + (size_t)(b * SS + j0 + key) * DD + h * DHD + c8;
      uint4 kv = *reinterpret_cast<const uint4*>(kp);
      *reinterpret_cast<uint4*>(&Ks[key][c8]) = kv;
      const bf16_t* vp = Vb + (size_t)(b * SS + j0 + key) * DD + h * DHD + c8;
      FragU f; f.u = *reinterpret_cast<const uint4*>(vp);
#pragma unroll
      for (int j = 0; j < 8; ++j) Vt[c8 + j][key] = f.e[j];   // transpose into LDS
    }
    __syncthreads();

    // S = Q @ K^T for 32 keys (two 16-col C-frags)
    floatx4 zz = {0.f,0.f,0.f,0.f};
    floatx4 slo = zz, shi = zz;
#pragma unroll
    for (int ks = 0; ks < 2; ++ks) {
      bf16x8 blo = ld_frag16(&Ks[l16][ks * 32 + quad * 8]);
      bf16x8 bhi = ld_frag16(&Ks[16 + l16][ks * 32 + quad * 8]);
      slo = __builtin_amdgcn_mfma_f32_16x16x32_bf16(qf[ks], blo, slo, 0, 0, 0);
      shi = __builtin_amdgcn_mfma_f32_16x16x32_bf16(qf[ks], bhi, shi, 0, 0, 0);
    }
    const int milo = b * SS + j0 + l16;
    const int mihi = milo + 16;
    const int mlo = mflag ? (int)((const signed char*)mask)[milo] : mask[milo];
    const int mhi = mflag ? (int)((const signed char*)mask)[mihi] : mask[mihi];

    // Online softmax per q-row (row = quad*4+reg; reduce across the 16 l16 lanes)
#pragma unroll
    for (int reg = 0; reg < 4; ++reg) {
      const float flo = mlo ? NEG : slo[reg] * SCALE;
      const float fhi = mhi ? NEG : shi[reg] * SCALE;
      float mx = fmaxf(flo, fhi);
#pragma unroll
      for (int off = 1; off < 16; off <<= 1) mx = fmaxf(mx, __shfl_xor(mx, off, 64));
      const float mn = fmaxf(m_i[reg], mx);
      const float alpha = __expf(m_i[reg] - mn);
      // guard: masked entries contribute exactly 0 even if mn == NEG sentinel
      const float plo = (flo < -0.5e30f) ? 0.f : __expf(flo - mn);
      const float phi = (fhi < -0.5e30f) ? 0.f : __expf(fhi - mn);
      float rs = plo + phi;
#pragma unroll
      for (int off = 1; off < 16; off <<= 1) rs += __shfl_xor(rs, off, 64);
      l_i[reg] = l_i[reg] * alpha + rs;
      m_i[reg] = mn;
#pragma unroll
      for (int nt = 0; nt < 4; ++nt) accO[nt][reg] *= alpha;
      Ps[w][quad * 4 + reg][l16]      = (bf16_t)plo;   // C-layout -> LDS
      Ps[w][quad * 4 + reg][16 + l16] = (bf16_t)phi;
    }
    __syncthreads();   // order Ps cross-lane write->read (and Vt vs next restage)

    // O += P @ V  (P A-layout from LDS, V^T rows K-major)
    bf16x8 pa = ld_frag16(&Ps[w][l16][quad * 8]);
#pragma unroll
    for (int nt = 0; nt < 4; ++nt) {
      bf16x8 vf = ld_frag16(&Vt[nt * 16 + l16][quad * 8]);
      accO[nt] = __builtin_amdgcn_mfma_f32_16x16x32_bf16(pa, vf, accO[nt], 0, 0, 0);
    }
  }

#pragma unroll
  for (int nt = 0; nt < 4; ++nt)
#pragma unroll
    for (int reg = 0; reg < 4; ++reg) {
      const int r = s0 + w * 16 + quad * 4 + reg;
      const int c = h * DHD + nt * 16 + l16;
      O[(size_t)(b * SS + r) * DD + c] = (bf16_t)(accO[nt][reg] / l_i[reg]);
    }
}

// ---------------------------------------------------------------------------
// y = LayerNorm(x + a) * g + b.  One block per row.  Alias-safe (Y==X ok).
// final_out!=0: write f32 if flags[0] says the problem runs in f32.
// ---------------------------------------------------------------------------
__global__ __launch_bounds__(256) void ln_add_k(const bf16_t* __restrict__ X,
                                                const bf16_t* __restrict__ A,
                                                const bf16_t* __restrict__ g,
                                                const bf16_t* __restrict__ bb,
                                                void* __restrict__ Yv,
                                                const int* __restrict__ flg,
                                                int final_out) {
  const int row = blockIdx.x;
  const int t = threadIdx.x;
  const int f32o = final_out ? flg[0] : 0;
  const bf16_t* xp = X + (size_t)row * DD;
  const bf16_t* ap = A + (size_t)row * DD;
  float v[4], s = 0.f, sq = 0.f;
#pragma unroll
  for (int i = 0; i < 4; ++i) {
    float xv = (float)xp[t + i * 256] + (float)ap[t + i * 256];
    v[i] = xv; s += xv; sq += xv * xv;
  }
#pragma unroll
  for (int off = 1; off < 64; off <<= 1) {
    s  += __shfl_xor(s, off, 64);
    sq += __shfl_xor(sq, off, 64);
  }
  __shared__ float red[2][4];
  const int w = t >> 6, lane = t & 63;
  if (lane == 0) { red[0][w] = s; red[1][w] = sq; }
  __syncthreads();
  s  = red[0][0] + red[0][1] + red[0][2] + red[0][3];
  sq = red[1][0] + red[1][1] + red[1][2] + red[1][3];
  const float mean = s * (1.f / 1024.f);
  const float var  = sq * (1.f / 1024.f) - mean * mean;
  const float rstd = rsqrtf(var + 1e-5f);
#pragma unroll
  for (int i = 0; i < 4; ++i) {
    const int c = t + i * 256;
    const float val = (v[i] - mean) * rstd * (float)g[c] + (float)bb[c];
    if (f32o) ((float*)Yv)[(size_t)row * DD + c] = val;
    else      ((bf16_t*)Yv)[(size_t)row * DD + c] = (bf16_t)val;
  }
}

// ---------------------------------------------------------------------------
// Beacon: encode a diagnostic constant into the output.
// ---------------------------------------------------------------------------
__global__ __launch_bounds__(256) void beacon_k(bf16_t* out, int n, float val) {
  int i = blockIdx.x * 256 + threadIdx.x;
  if (i < n) out[i] = (bf16_t)val;
}

// ---------------------------------------------------------------------------
extern "C" void kernel_launch(void* const* d_in, const int* in_sizes, int n_in,
                              void* d_out, int out_size, void* d_ws, size_t ws_size,
                              hipStream_t stream) {
  const dim3 blk(256);
  const dim3 gB((out_size + 255) / 256);

  static const int expect[24] = {
    4194304, 4194304,
    1048576, 1048576, 1048576, 1048576, 1024,
    1048576, 1048576, 1048576, 1048576, 1024,
    1024, 1024, 1024, 1024, 1024, 1024,
    4194304, 4096,
    4194304, 1024,
    4096, 4096
  };
  if (n_in != 24) {
    beacon_k<<<gB, blk, 0, stream>>>((bf16_t*)d_out, out_size, 200.f + (float)(n_in & 63));
    return;
  }
  for (int i = 0; i < 24; ++i) {
    if (in_sizes[i] != expect[i]) {
      beacon_k<<<gB, blk, 0, stream>>>((bf16_t*)d_out, out_size, 20.f + 2.f * (float)i);
      return;
    }
  }

  const void* x_raw   = d_in[0];
  const void* enc_raw = d_in[1];
  const void* sa_wq = d_in[2], *sa_wk = d_in[3], *sa_wv = d_in[4], *sa_wo = d_in[5];
  const void* sa_bo = d_in[6];
  const void* ca_wq = d_in[7], *ca_wk = d_in[8], *ca_wv = d_in[9], *ca_wo = d_in[10];
  const void* ca_bo = d_in[11];
  const void* ln1_g = d_in[12], *ln1_b = d_in[13];
  const void* ln2_g = d_in[14], *ln2_b = d_in[15];
  const void* ln3_g = d_in[16], *ln3_b = d_in[17];
  const void* fc1_w = d_in[18], *fc1_b = d_in[19];
  const void* fc2_w = d_in[20], *fc2_b = d_in[21];
  const int* tgt_mask = (const int*)d_in[22];
  const int* src_mask = (const int*)d_in[23];

  const size_t SEG = (size_t)NROWS * DD;           // 4,194,304 elems = 8 MiB bf16
  const size_t PS_ELEMS = 32768;
  if (ws_size < (8 * SEG + PS_ELEMS) * sizeof(bf16_t)) {
    beacon_k<<<gB, blk, 0, stream>>>((bf16_t*)d_out, out_size, 7.f);
    return;
  }
  bf16_t* ws = (bf16_t*)d_ws;
  bf16_t* qb = ws + 0 * SEG;        // q / attn-out t0
  bf16_t* kb = ws + 1 * SEG;
  bf16_t* vb = ws + 2 * SEG;        // v / MLP h-chunk (chunked path)
  bf16_t* wt = ws + 3 * SEG;        // current transposed weight
  bf16_t* t1 = ws + 4 * SEG;
  bf16_t* x1 = ws + 5 * SEG;        // ln1 out; ln2 in-place out (x2)
  bf16_t* xc = ws + 6 * SEG;        // canonical bf16 x
  bf16_t* ec = ws + 7 * SEG;        // canonical bf16 enc
  bf16_t* ps = ws + 8 * SEG;        // canonical small params
  int*    fl = (int*)(ps + 16384);  // flags
  bf16_t* t0 = qb;
  bf16_t* x2 = x1;
  const bool big_ws = ws_size >= (12 * SEG + PS_ELEMS) * sizeof(bf16_t);
  bf16_t* hb = ws + 8 * SEG + PS_ELEMS;

  bf16_t* c_ln1g = ps + 0,    *c_ln1b = ps + 1024;
  bf16_t* c_ln2g = ps + 2048, *c_ln2b = ps + 3072;
  bf16_t* c_ln3g = ps + 4096, *c_ln3b = ps + 5120;
  bf16_t* c_sabo = ps + 6144, *c_cabo = ps + 7168;
  bf16_t* c_f1b  = ps + 8192;
  bf16_t* c_f2b  = ps + 12288;

  const dim3 gT(16, 16);
  const dim3 gG(DD / 128, NROWS / 64);
  const dim3 gA(SS / 64, BB * HH);   // (32, 32) flash-attn grid
  const dim3 gL(NROWS);
  const dim3 gC(512);

  // ---- detect dtypes, canonicalize ----
  detect_k<<<dim3(1), blk, 0, stream>>>(x_raw, enc_raw, fc1_w, tgt_mask, fl);
  cvt_k<<<gC, blk, 0, stream>>>(x_raw,   xc, (int)SEG, fl);
  cvt_k<<<gC, blk, 0, stream>>>(enc_raw, ec, (int)SEG, fl);
  cvt_k<<<dim3(4), blk, 0, stream>>>(ln1_g, c_ln1g, 1024, fl);
  cvt_k<<<dim3(4), blk, 0, stream>>>(ln1_b, c_ln1b, 1024, fl);
  cvt_k<<<dim3(4), blk, 0, stream>>>(ln2_g, c_ln2g, 1024, fl);
  cvt_k<<<dim3(4), blk, 0, stream>>>(ln2_b, c_ln2b, 1024, fl);
  cvt_k<<<dim3(4), blk, 0, stream>>>(ln3_g, c_ln3g, 1024, fl);
  cvt_k<<<dim3(4), blk, 0, stream>>>(ln3_b, c_ln3b, 1024, fl);
  cvt_k<<<dim3(4), blk, 0, stream>>>(sa_bo, c_sabo, 1024, fl);
  cvt_k<<<dim3(4), blk, 0, stream>>>(ca_bo, c_cabo, 1024, fl);
  cvt_k<<<dim3(16), blk, 0, stream>>>(fc1_b, c_f1b, 4096, fl);
  cvt_k<<<dim3(4), blk, 0, stream>>>(fc2_b, c_f2b, 1024, fl);

  // ---- self attention ----
  transpose_k<<<gT, blk, 0, stream>>>(sa_wq, wt, DD, DD, fl);
  gemm_nt<0,0><<<gG, blk, 0, stream>>>(xc, wt, nullptr, qb, NROWS, DD, DD);
  transpose_k<<<gT, blk, 0, stream>>>(sa_wk, wt, DD, DD, fl);
  gemm_nt<0,0><<<gG, blk, 0, stream>>>(xc, wt, nullptr, kb, NROWS, DD, DD);
  transpose_k<<<gT, blk, 0, stream>>>(sa_wv, wt, DD, DD, fl);
  gemm_nt<0,0><<<gG, blk, 0, stream>>>(xc, wt, nullptr, vb, NROWS, DD, DD);
  attn_k<<<gA, blk, 0, stream>>>(qb, kb, vb, tgt_mask, t0, fl);
  transpose_k<<<gT, blk, 0, stream>>>(sa_wo, wt, DD, DD, fl);
  gemm_nt<1,0><<<gG, blk, 0, stream>>>(t0, wt, c_sabo, t1, NROWS, DD, DD);
  ln_add_k<<<gL, blk, 0, stream>>>(xc, t1, c_ln1g, c_ln1b, x1, fl, 0);

  // ---- cross attention ----
  transpose_k<<<gT, blk, 0, stream>>>(ca_wq, wt, DD, DD, fl);
  gemm_nt<0,0><<<gG, blk, 0, stream>>>(x1, wt, nullptr, qb, NROWS, DD, DD);
  transpose_k<<<gT, blk, 0, stream>>>(ca_wk, wt, DD, DD, fl);
  gemm_nt<0,0><<<gG, blk, 0, stream>>>(ec, wt, nullptr, kb, NROWS, DD, DD);
  transpose_k<<<gT, blk, 0, stream>>>(ca_wv, wt, DD, DD, fl);
  gemm_nt<0,0><<<gG, blk, 0, stream>>>(ec, wt, nullptr, vb, NROWS, DD, DD);
  attn_k<<<gA, blk, 0, stream>>>(qb, kb, vb, src_mask, t0, fl);
  transpose_k<<<gT, blk, 0, stream>>>(ca_wo, wt, DD, DD, fl);
  gemm_nt<1,0><<<gG, blk, 0, stream>>>(t0, wt, c_cabo, t1, NROWS, DD, DD);
  ln_add_k<<<gL, blk, 0, stream>>>(x1, t1, c_ln2g, c_ln2b, x2, fl, 0);

  // ---- MLP ----
  transpose_k<<<dim3(FFD/64, DD/64), blk, 0, stream>>>(fc1_w, wt, DD, FFD, fl);  // fc1^T
  if (big_ws) {
    gemm_nt<1,1><<<dim3(FFD/128, NROWS/64), blk, 0, stream>>>(x2, wt, c_f1b, hb, NROWS, FFD, DD);
    transpose_k<<<dim3(DD/64, FFD/64), blk, 0, stream>>>(fc2_w, wt, FFD, DD, fl); // fc2^T
    gemm_nt<1,0><<<dim3(DD/128,  NROWS/64), blk, 0, stream>>>(hb, wt, c_f2b, t1, NROWS, DD, FFD);
  } else {
    transpose_k<<<dim3(DD/64, FFD/64), blk, 0, stream>>>(fc2_w, kb, FFD, DD, fl); // fc2^T in kb
    for (int c = 0; c < 4; ++c) {
      gemm_nt<1,1><<<dim3(FFD/128, 16), blk, 0, stream>>>(x2 + (size_t)c*1024*DD, wt, c_f1b, vb, 1024, FFD, DD);
      gemm_nt<1,0><<<dim3(DD/128,  16), blk, 0, stream>>>(vb, kb, c_f2b, t1 + (size_t)c*1024*DD, 1024, DD, FFD);
    }
  }
  ln_add_k<<<gL, blk, 0, stream>>>(x2, t1, c_ln3g, c_ln3b, d_out, fl, 1);
}

// Round 6
// 994.434 us; speedup vs baseline: 6.0598x; 1.0627x over previous
//
#include <hip/hip_runtime.h>
#include <hip/hip_bf16.h>
#include <math.h>

// Problem constants (B=2, S=2048, D=1024, H=16, DH=64, FF=4096)
#define BB 2
#define SS 2048
#define DD 1024
#define HH 16
#define DHD 64
#define FFD 4096
#define NROWS (BB*SS)

typedef __bf16 bf16_t;
typedef __bf16 bf16x8 __attribute__((ext_vector_type(8)));
typedef float floatx4 __attribute__((ext_vector_type(4)));

union FragU { uint4 u; bf16x8 v; bf16_t e[8]; };

static __device__ __forceinline__ bf16x8 ld_frag16(const bf16_t* p) {
  FragU f; f.u = *reinterpret_cast<const uint4*>(p); return f.v;
}

// async global->LDS 16B: lane i of the wave lands at lptr + i*16 (wave-uniform base!)
static __device__ __forceinline__ void gl_lds16(const bf16_t* g, bf16_t* l) {
  __builtin_amdgcn_global_load_lds(
      (const __attribute__((address_space(1))) unsigned int*)g,
      (__attribute__((address_space(3))) unsigned int*)l, 16, 0, 0);
}

// ---------------------------------------------------------------------------
// Detector: flags[0]=1 if float tensors are really f32; flags[1]=1 if masks int8.
// ---------------------------------------------------------------------------
__global__ __launch_bounds__(256) void detect_k(const void* __restrict__ xp,
                                                const void* __restrict__ ep,
                                                const void* __restrict__ wp,
                                                const int* __restrict__ mk,
                                                int* __restrict__ flags) {
  const int t = threadIdx.x;
  const unsigned short* a = (const unsigned short*)xp;
  const unsigned short* b = (const unsigned short*)ep;
  const unsigned short* c = (const unsigned short*)wp;
  int bad = 0, mbad = 0;
  for (int i = t; i < 4096; i += 256) {
    int e1 = (a[i] >> 7) & 0xFF, e2 = (b[i] >> 7) & 0xFF, e3 = (c[i] >> 7) & 0xFF;
    if (e1 >= 0x9B || e2 >= 0x9B || e3 >= 0x9B) bad = 1;
  }
  for (int i = t; i < 1024; i += 256) {
    unsigned v = (unsigned)mk[i];
    if (v > 1u) mbad = 1;
  }
  __shared__ int s0, s1;
  if (t == 0) { s0 = 0; s1 = 0; }
  __syncthreads();
  if (bad)  atomicOr(&s0, 1);
  if (mbad) atomicOr(&s1, 1);
  __syncthreads();
  if (t == 0) { flags[0] = s0; flags[1] = s1; }
}

// ---------------------------------------------------------------------------
// Canonicalize a float tensor to bf16 (copy if already bf16).
// ---------------------------------------------------------------------------
__global__ __launch_bounds__(256) void cvt_k(const void* __restrict__ src,
                                             bf16_t* __restrict__ dst, int n,
                                             const int* __restrict__ flg) {
  const int f32m = flg[0];
  const int idx = blockIdx.x * 256 + threadIdx.x;
  const int stride = gridDim.x * 256;
  if (f32m) {
    const float* s = (const float*)src;
    for (int i = idx; i < n; i += stride) dst[i] = (bf16_t)s[i];
  } else {
    const bf16_t* s = (const bf16_t*)src;
    for (int i = idx; i < n; i += stride) dst[i] = s[i];
  }
}

// ---------------------------------------------------------------------------
// Transpose raw weight (f32 or bf16 per flag) -> bf16 out[c][r].
// rows,cols multiples of 64.  grid (cols/64, rows/64), block 256.
// ---------------------------------------------------------------------------
__global__ __launch_bounds__(256) void transpose_k(const void* __restrict__ inv,
                                                   bf16_t* __restrict__ out,
                                                   int rows, int cols,
                                                   const int* __restrict__ flg) {
  __shared__ __align__(16) bf16_t tile[64][72];
  const int f32m = flg[0];
  const int c0 = blockIdx.x * 64, r0 = blockIdx.y * 64;
  const int t  = threadIdx.x;
  const int lr = t >> 3;            // 0..31
  const int lc = (t & 7) * 8;       // 0..56
#pragma unroll
  for (int half = 0; half < 2; ++half) {
    int r = lr + half * 32;
    if (f32m) {
      const float* p = (const float*)inv + (size_t)(r0 + r) * cols + c0 + lc;
      float4 q0 = *reinterpret_cast<const float4*>(p);
      float4 q1 = *reinterpret_cast<const float4*>(p + 4);
      tile[r][lc+0] = (bf16_t)q0.x; tile[r][lc+1] = (bf16_t)q0.y;
      tile[r][lc+2] = (bf16_t)q0.z; tile[r][lc+3] = (bf16_t)q0.w;
      tile[r][lc+4] = (bf16_t)q1.x; tile[r][lc+5] = (bf16_t)q1.y;
      tile[r][lc+6] = (bf16_t)q1.z; tile[r][lc+7] = (bf16_t)q1.w;
    } else {
      uint4 vv = *reinterpret_cast<const uint4*>((const bf16_t*)inv + (size_t)(r0 + r) * cols + c0 + lc);
      *reinterpret_cast<uint4*>(&tile[r][lc]) = vv;
    }
  }
  __syncthreads();
#pragma unroll
  for (int half = 0; half < 2; ++half) {
    int oc = lr + half * 32;
    FragU f;
#pragma unroll
    for (int j = 0; j < 8; ++j) f.e[j] = tile[lc + j][oc];
    *reinterpret_cast<uint4*>(out + (size_t)(c0 + oc) * rows + r0 + lc) = f.u;
  }
}

// ---------------------------------------------------------------------------
// GEMM (m97-style): C[M,N] = A[M,K] @ Bt[N,K]^T (+bias, +GELU).
// 128x128 tile, BK=32, 256 thr = 4 waves, each wave 64x64 (4x4 16x16x32 frags).
// Staging via global_load_lds width=16 into UNPADDED [128][32] LDS tiles
// (row stride 64B = 16 banks; frag b128 reads are conflict-free).
// grid (N/128, M/128).  M,N,K multiples of 128/128/32.
// ---------------------------------------------------------------------------
template<int BIAS, int GELU>
__global__ __launch_bounds__(256) void gemm_nt(const bf16_t* __restrict__ A,
                                               const bf16_t* __restrict__ Bt,
                                               const bf16_t* __restrict__ bias,
                                               bf16_t* __restrict__ C,
                                               int M, int N, int K) {
  __shared__ __align__(16) bf16_t As[128 * 32];
  __shared__ __align__(16) bf16_t Bs[128 * 32];
  const int m0 = blockIdx.y * 128, n0 = blockIdx.x * 128;
  const int t = threadIdx.x, lane = t & 63, w = t >> 6;
  const int quad = lane >> 4, l16 = lane & 15;
  const int wy = w >> 1, wx = w & 1;

  floatx4 acc[4][4];
#pragma unroll
  for (int i = 0; i < 4; ++i)
#pragma unroll
    for (int j = 0; j < 4; ++j) { floatx4 z = {0.f,0.f,0.f,0.f}; acc[i][j] = z; }

  // staging: chunk c (0..7) = rows c*16..c*16+15; lane -> row c*16+(lane>>2),
  // 16B at col (lane&3)*8.  LDS offset == lane*16 from chunk base (contiguity!)
  const int srow = lane >> 2;
  const int scol = (lane & 3) * 8;

  for (int k0 = 0; k0 < K; k0 += 32) {
    __syncthreads();                 // prev-iter frag reads done before overwrite
#pragma unroll
    for (int c = 0; c < 2; ++c) {
      const int chunk = w * 2 + c;   // this wave's chunks
      const int r = chunk * 16 + srow;
      gl_lds16(A  + (size_t)(m0 + r) * K + k0 + scol, As + chunk * 512);
      gl_lds16(Bt + (size_t)(n0 + r) * K + k0 + scol, Bs + chunk * 512);
    }
    __syncthreads();                 // drains vmcnt(0) -> LDS visible

    bf16x8 af[4], bfr[4];
#pragma unroll
    for (int mt = 0; mt < 4; ++mt) af[mt]  = ld_frag16(As + (wy*64 + mt*16 + l16) * 32 + quad*8);
#pragma unroll
    for (int nt = 0; nt < 4; ++nt) bfr[nt] = ld_frag16(Bs + (wx*64 + nt*16 + l16) * 32 + quad*8);
#pragma unroll
    for (int mt = 0; mt < 4; ++mt)
#pragma unroll
      for (int nt = 0; nt < 4; ++nt)
        acc[mt][nt] = __builtin_amdgcn_mfma_f32_16x16x32_bf16(af[mt], bfr[nt], acc[mt][nt], 0, 0, 0);
  }

  // Epilogue: C/D layout row = quad*4+reg, col = l16.
#pragma unroll
  for (int nt = 0; nt < 4; ++nt) {
    const int c = n0 + wx*64 + nt*16 + l16;
    float bv = 0.f;
    if (BIAS) bv = (float)bias[c];
#pragma unroll
    for (int mt = 0; mt < 4; ++mt) {
      const int rb = m0 + wy*64 + mt*16 + quad*4;
#pragma unroll
      for (int reg = 0; reg < 4; ++reg) {
        float v2 = acc[mt][nt][reg] + bv;
        if (GELU) v2 = 0.5f * v2 * (1.f + erff(v2 * 0.70710678118654752f));
        C[(size_t)(rb + reg) * N + c] = (bf16_t)v2;
      }
    }
  }
}

// ---------------------------------------------------------------------------
// MFMA flash attention.  Q,K,V: [B*S, 1024] bf16, head h = cols h*64..h*64+63.
// grid (S/64, B*H), block 256 (4 waves, wave = 16 q-rows).  32-key tiles.
// Vt uses a 16B-chunk XOR swizzle (c' = chunk ^ ((dh>>3)&3)) -> conflict-free
// transpose writes AND b128 fragment reads (was 8-way-conflict hotspot).
// ---------------------------------------------------------------------------
__global__ __launch_bounds__(256) void attn_k(const bf16_t* __restrict__ Q,
                                              const bf16_t* __restrict__ Kb,
                                              const bf16_t* __restrict__ Vb,
                                              const int* __restrict__ mask,
                                              bf16_t* __restrict__ O,
                                              const int* __restrict__ flg) {
  __shared__ __align__(16) bf16_t Ks[32][72];     // [key][dh]
  __shared__ __align__(16) bf16_t Vt[64 * 72];    // [dh][key-chunk-swizzled]
  __shared__ __align__(16) bf16_t Ps[4][16][40];  // per-wave P: [qrow][key]
  const int mflag = flg[1];
  const int bh = blockIdx.y;
  const int b = bh >> 4, h = bh & 15;
  const int s0 = blockIdx.x * 64;
  const int t = threadIdx.x, w = t >> 6, lane = t & 63;
  const int quad = lane >> 4, l16 = lane & 15;
  const float NEG = -1.0e30f;
  const float SCALE = 0.125f;       // 64^-0.5

  // Q A-fragments (m = l16, k = quad*8+j), 2 K=32 steps over DH=64
  bf16x8 qf[2];
  {
    const int r = s0 + w * 16 + l16;
    const bf16_t* qp = Q + (size_t)(b * SS + r) * DD + h * DHD;
#pragma unroll
    for (int ks = 0; ks < 2; ++ks) qf[ks] = ld_frag16(qp + ks * 32 + quad * 8);
  }

  float m_i[4], l_i[4];
  floatx4 accO[4];
#pragma unroll
  for (int i = 0; i < 4; ++i) {
    m_i[i] = NEG; l_i[i] = 0.f;
    floatx4 z = {0.f,0.f,0.f,0.f}; accO[i] = z;
  }

  const int key = t >> 3;           // 0..31 staging row
  const int c8  = (t & 7) * 8;      // 0..56 staging col
  const int vcp = (key >> 3) ^ (t & 3);   // chunk' = (key>>3) ^ ((dh>>3)&3), dh>>3 = t&7

  for (int j0 = 0; j0 < SS; j0 += 32) {
    __syncthreads();                // prev-iter Ks/Vt reads done before restage
    {
      const bf16_t* kp = Kb + (size_t)(b * SS + j0 + key) * DD + h * DHD + c8;
      uint4 kv = *reinterpret_cast<const uint4*>(kp);
      *reinterpret_cast<uint4*>(&Ks[key][c8]) = kv;
      const bf16_t* vp = Vb + (size_t)(b * SS + j0 + key) * DD + h * DHD + c8;
      FragU f; f.u = *reinterpret_cast<const uint4*>(vp);
#pragma unroll
      for (int j = 0; j < 8; ++j)   // swizzled transpose: (dh=c8+j, key)
        Vt[(c8 + j) * 72 + vcp * 8 + (key & 7)] = f.e[j];
    }
    __syncthreads();

    // S = Q @ K^T for 32 keys (two 16-col C-frags)
    floatx4 zz = {0.f,0.f,0.f,0.f};
    floatx4 slo = zz, shi = zz;
#pragma unroll
    for (int ks = 0; ks < 2; ++ks) {
      bf16x8 blo = ld_frag16(&Ks[l16][ks * 32 + quad * 8]);
      bf16x8 bhi = ld_frag16(&Ks[16 + l16][ks * 32 + quad * 8]);
      slo = __builtin_amdgcn_mfma_f32_16x16x32_bf16(qf[ks], blo, slo, 0, 0, 0);
      shi = __builtin_amdgcn_mfma_f32_16x16x32_bf16(qf[ks], bhi, shi, 0, 0, 0);
    }
    const int milo = b * SS + j0 + l16;
    const int mihi = milo + 16;
    const int mlo = mflag ? (int)((const signed char*)mask)[milo] : mask[milo];
    const int mhi = mflag ? (int)((const signed char*)mask)[mihi] : mask[mihi];

    // Online softmax per q-row (row = quad*4+reg; reduce across the 16 l16 lanes)
#pragma unroll
    for (int reg = 0; reg < 4; ++reg) {
      const float flo = mlo ? NEG : slo[reg] * SCALE;
      const float fhi = mhi ? NEG : shi[reg] * SCALE;
      float mx = fmaxf(flo, fhi);
#pragma unroll
      for (int off = 1; off < 16; off <<= 1) mx = fmaxf(mx, __shfl_xor(mx, off, 64));
      const float mn = fmaxf(m_i[reg], mx);
      const float alpha = __expf(m_i[reg] - mn);
      const float plo = (flo < -0.5e30f) ? 0.f : __expf(flo - mn);
      const float phi = (fhi < -0.5e30f) ? 0.f : __expf(fhi - mn);
      float rs = plo + phi;
#pragma unroll
      for (int off = 1; off < 16; off <<= 1) rs += __shfl_xor(rs, off, 64);
      l_i[reg] = l_i[reg] * alpha + rs;
      m_i[reg] = mn;
#pragma unroll
      for (int nt = 0; nt < 4; ++nt) accO[nt][reg] *= alpha;
      Ps[w][quad * 4 + reg][l16]      = (bf16_t)plo;   // C-layout -> LDS
      Ps[w][quad * 4 + reg][16 + l16] = (bf16_t)phi;
    }
    __syncthreads();   // order Ps cross-lane write->read (and Vt vs next restage)

    // O += P @ V  (P A-layout from LDS; V B-operand from swizzled Vt)
    bf16x8 pa = ld_frag16(&Ps[w][l16][quad * 8]);
#pragma unroll
    for (int nt = 0; nt < 4; ++nt) {
      const int dh = nt * 16 + l16;
      const int cp = quad ^ ((dh >> 3) & 3);
      bf16x8 vf = ld_frag16(&Vt[dh * 72 + cp * 8]);
      accO[nt] = __builtin_amdgcn_mfma_f32_16x16x32_bf16(pa, vf, accO[nt], 0, 0, 0);
    }
  }

#pragma unroll
  for (int nt = 0; nt < 4; ++nt)
#pragma unroll
    for (int reg = 0; reg < 4; ++reg) {
      const int r = s0 + w * 16 + quad * 4 + reg;
      const int c = h * DHD + nt * 16 + l16;
      O[(size_t)(b * SS + r) * DD + c] = (bf16_t)(accO[nt][reg] / l_i[reg]);
    }
}

// ---------------------------------------------------------------------------
// y = LayerNorm(x + a) * g + b.  One block per row.  Alias-safe (Y==X ok).
// final_out!=0: write f32 if flags[0] says the problem runs in f32.
// ---------------------------------------------------------------------------
__global__ __launch_bounds__(256) void ln_add_k(const bf16_t* __restrict__ X,
                                                const bf16_t* __restrict__ A,
                                                const bf16_t* __restrict__ g,
                                                const bf16_t* __restrict__ bb,
                                                void* __restrict__ Yv,
                                                const int* __restrict__ flg,
                                                int final_out) {
  const int row = blockIdx.x;
  const int t = threadIdx.x;
  const int f32o = final_out ? flg[0] : 0;
  const bf16_t* xp = X + (size_t)row * DD;
  const bf16_t* ap = A + (size_t)row * DD;
  float v[4], s = 0.f, sq = 0.f;
#pragma unroll
  for (int i = 0; i < 4; ++i) {
    float xv = (float)xp[t + i * 256] + (float)ap[t + i * 256];
    v[i] = xv; s += xv; sq += xv * xv;
  }
#pragma unroll
  for (int off = 1; off < 64; off <<= 1) {
    s  += __shfl_xor(s, off, 64);
    sq += __shfl_xor(sq, off, 64);
  }
  __shared__ float red[2][4];
  const int w = t >> 6, lane = t & 63;
  if (lane == 0) { red[0][w] = s; red[1][w] = sq; }
  __syncthreads();
  s  = red[0][0] + red[0][1] + red[0][2] + red[0][3];
  sq = red[1][0] + red[1][1] + red[1][2] + red[1][3];
  const float mean = s * (1.f / 1024.f);
  const float var  = sq * (1.f / 1024.f) - mean * mean;
  const float rstd = rsqrtf(var + 1e-5f);
#pragma unroll
  for (int i = 0; i < 4; ++i) {
    const int c = t + i * 256;
    const float val = (v[i] - mean) * rstd * (float)g[c] + (float)bb[c];
    if (f32o) ((float*)Yv)[(size_t)row * DD + c] = val;
    else      ((bf16_t*)Yv)[(size_t)row * DD + c] = (bf16_t)val;
  }
}

// ---------------------------------------------------------------------------
__global__ __launch_bounds__(256) void beacon_k(bf16_t* out, int n, float val) {
  int i = blockIdx.x * 256 + threadIdx.x;
  if (i < n) out[i] = (bf16_t)val;
}

// ---------------------------------------------------------------------------
extern "C" void kernel_launch(void* const* d_in, const int* in_sizes, int n_in,
                              void* d_out, int out_size, void* d_ws, size_t ws_size,
                              hipStream_t stream) {
  const dim3 blk(256);
  const dim3 gB((out_size + 255) / 256);

  static const int expect[24] = {
    4194304, 4194304,
    1048576, 1048576, 1048576, 1048576, 1024,
    1048576, 1048576, 1048576, 1048576, 1024,
    1024, 1024, 1024, 1024, 1024, 1024,
    4194304, 4096,
    4194304, 1024,
    4096, 4096
  };
  if (n_in != 24) {
    beacon_k<<<gB, blk, 0, stream>>>((bf16_t*)d_out, out_size, 200.f + (float)(n_in & 63));
    return;
  }
  for (int i = 0; i < 24; ++i) {
    if (in_sizes[i] != expect[i]) {
      beacon_k<<<gB, blk, 0, stream>>>((bf16_t*)d_out, out_size, 20.f + 2.f * (float)i);
      return;
    }
  }

  const void* x_raw   = d_in[0];
  const void* enc_raw = d_in[1];
  const void* sa_wq = d_in[2], *sa_wk = d_in[3], *sa_wv = d_in[4], *sa_wo = d_in[5];
  const void* sa_bo = d_in[6];
  const void* ca_wq = d_in[7], *ca_wk = d_in[8], *ca_wv = d_in[9], *ca_wo = d_in[10];
  const void* ca_bo = d_in[11];
  const void* ln1_g = d_in[12], *ln1_b = d_in[13];
  const void* ln2_g = d_in[14], *ln2_b = d_in[15];
  const void* ln3_g = d_in[16], *ln3_b = d_in[17];
  const void* fc1_w = d_in[18], *fc1_b = d_in[19];
  const void* fc2_w = d_in[20], *fc2_b = d_in[21];
  const int* tgt_mask = (const int*)d_in[22];
  const int* src_mask = (const int*)d_in[23];

  const size_t SEG = (size_t)NROWS * DD;           // 4,194,304 elems = 8 MiB bf16
  const size_t PS_ELEMS = 32768;
  if (ws_size < (8 * SEG + PS_ELEMS) * sizeof(bf16_t)) {
    beacon_k<<<gB, blk, 0, stream>>>((bf16_t*)d_out, out_size, 7.f);
    return;
  }
  bf16_t* ws = (bf16_t*)d_ws;
  bf16_t* qb = ws + 0 * SEG;        // q / attn-out t0
  bf16_t* kb = ws + 1 * SEG;
  bf16_t* vb = ws + 2 * SEG;        // v / MLP h-chunk (chunked path)
  bf16_t* wt = ws + 3 * SEG;        // current transposed weight
  bf16_t* t1 = ws + 4 * SEG;
  bf16_t* x1 = ws + 5 * SEG;        // ln1 out; ln2 in-place out (x2)
  bf16_t* xc = ws + 6 * SEG;        // canonical bf16 x
  bf16_t* ec = ws + 7 * SEG;        // canonical bf16 enc
  bf16_t* ps = ws + 8 * SEG;        // canonical small params
  int*    fl = (int*)(ps + 16384);  // flags
  bf16_t* t0 = qb;
  bf16_t* x2 = x1;
  const bool big_ws = ws_size >= (12 * SEG + PS_ELEMS) * sizeof(bf16_t);
  bf16_t* hb = ws + 8 * SEG + PS_ELEMS;

  bf16_t* c_ln1g = ps + 0,    *c_ln1b = ps + 1024;
  bf16_t* c_ln2g = ps + 2048, *c_ln2b = ps + 3072;
  bf16_t* c_ln3g = ps + 4096, *c_ln3b = ps + 5120;
  bf16_t* c_sabo = ps + 6144, *c_cabo = ps + 7168;
  bf16_t* c_f1b  = ps + 8192;
  bf16_t* c_f2b  = ps + 12288;

  const dim3 gT(16, 16);
  const dim3 gG(DD / 128, NROWS / 128);   // (8, 32) projection GEMMs
  const dim3 gA(SS / 64, BB * HH);        // (32, 32) flash-attn grid
  const dim3 gL(NROWS);
  const dim3 gC(512);

  // ---- detect dtypes, canonicalize ----
  detect_k<<<dim3(1), blk, 0, stream>>>(x_raw, enc_raw, fc1_w, tgt_mask, fl);
  cvt_k<<<gC, blk, 0, stream>>>(x_raw,   xc, (int)SEG, fl);
  cvt_k<<<gC, blk, 0, stream>>>(enc_raw, ec, (int)SEG, fl);
  cvt_k<<<dim3(4), blk, 0, stream>>>(ln1_g, c_ln1g, 1024, fl);
  cvt_k<<<dim3(4), blk, 0, stream>>>(ln1_b, c_ln1b, 1024, fl);
  cvt_k<<<dim3(4), blk, 0, stream>>>(ln2_g, c_ln2g, 1024, fl);
  cvt_k<<<dim3(4), blk, 0, stream>>>(ln2_b, c_ln2b, 1024, fl);
  cvt_k<<<dim3(4), blk, 0, stream>>>(ln3_g, c_ln3g, 1024, fl);
  cvt_k<<<dim3(4), blk, 0, stream>>>(ln3_b, c_ln3b, 1024, fl);
  cvt_k<<<dim3(4), blk, 0, stream>>>(sa_bo, c_sabo, 1024, fl);
  cvt_k<<<dim3(4), blk, 0, stream>>>(ca_bo, c_cabo, 1024, fl);
  cvt_k<<<dim3(16), blk, 0, stream>>>(fc1_b, c_f1b, 4096, fl);
  cvt_k<<<dim3(4), blk, 0, stream>>>(fc2_b, c_f2b, 1024, fl);

  // ---- self attention ----
  transpose_k<<<gT, blk, 0, stream>>>(sa_wq, wt, DD, DD, fl);
  gemm_nt<0,0><<<gG, blk, 0, stream>>>(xc, wt, nullptr, qb, NROWS, DD, DD);
  transpose_k<<<gT, blk, 0, stream>>>(sa_wk, wt, DD, DD, fl);
  gemm_nt<0,0><<<gG, blk, 0, stream>>>(xc, wt, nullptr, kb, NROWS, DD, DD);
  transpose_k<<<gT, blk, 0, stream>>>(sa_wv, wt, DD, DD, fl);
  gemm_nt<0,0><<<gG, blk, 0, stream>>>(xc, wt, nullptr, vb, NROWS, DD, DD);
  attn_k<<<gA, blk, 0, stream>>>(qb, kb, vb, tgt_mask, t0, fl);
  transpose_k<<<gT, blk, 0, stream>>>(sa_wo, wt, DD, DD, fl);
  gemm_nt<1,0><<<gG, blk, 0, stream>>>(t0, wt, c_sabo, t1, NROWS, DD, DD);
  ln_add_k<<<gL, blk, 0, stream>>>(xc, t1, c_ln1g, c_ln1b, x1, fl, 0);

  // ---- cross attention ----
  transpose_k<<<gT, blk, 0, stream>>>(ca_wq, wt, DD, DD, fl);
  gemm_nt<0,0><<<gG, blk, 0, stream>>>(x1, wt, nullptr, qb, NROWS, DD, DD);
  transpose_k<<<gT, blk, 0, stream>>>(ca_wk, wt, DD, DD, fl);
  gemm_nt<0,0><<<gG, blk, 0, stream>>>(ec, wt, nullptr, kb, NROWS, DD, DD);
  transpose_k<<<gT, blk, 0, stream>>>(ca_wv, wt, DD, DD, fl);
  gemm_nt<0,0><<<gG, blk, 0, stream>>>(ec, wt, nullptr, vb, NROWS, DD, DD);
  attn_k<<<gA, blk, 0, stream>>>(qb, kb, vb, src_mask, t0, fl);
  transpose_k<<<gT, blk, 0, stream>>>(ca_wo, wt, DD, DD, fl);
  gemm_nt<1,0><<<gG, blk, 0, stream>>>(t0, wt, c_cabo, t1, NROWS, DD, DD);
  ln_add_k<<<gL, blk, 0, stream>>>(x1, t1, c_ln2g, c_ln2b, x2, fl, 0);

  // ---- MLP ----
  transpose_k<<<dim3(FFD/64, DD/64), blk, 0, stream>>>(fc1_w, wt, DD, FFD, fl);  // fc1^T
  if (big_ws) {
    gemm_nt<1,1><<<dim3(FFD/128, NROWS/128), blk, 0, stream>>>(x2, wt, c_f1b, hb, NROWS, FFD, DD);
    transpose_k<<<dim3(DD/64, FFD/64), blk, 0, stream>>>(fc2_w, wt, FFD, DD, fl); // fc2^T
    gemm_nt<1,0><<<dim3(DD/128,  NROWS/128), blk, 0, stream>>>(hb, wt, c_f2b, t1, NROWS, DD, FFD);
  } else {
    transpose_k<<<dim3(DD/64, FFD/64), blk, 0, stream>>>(fc2_w, kb, FFD, DD, fl); // fc2^T in kb
    for (int c = 0; c < 4; ++c) {
      gemm_nt<1,1><<<dim3(FFD/128, 8), blk, 0, stream>>>(x2 + (size_t)c*1024*DD, wt, c_f1b, vb, 1024, FFD, DD);
      gemm_nt<1,0><<<dim3(DD/128,  8), blk, 0, stream>>>(vb, kb, c_f2b, t1 + (size_t)c*1024*DD, 1024, DD, FFD);
    }
  }
  ln_add_k<<<gL, blk, 0, stream>>>(x2, t1, c_ln3g, c_ln3b, d_out, fl, 1);
}

// Round 7
// 840.286 us; speedup vs baseline: 7.1715x; 1.1834x over previous
//
#include <hip/hip_runtime.h>
#include <hip/hip_bf16.h>
#include <math.h>

// Problem constants (B=2, S=2048, D=1024, H=16, DH=64, FF=4096)
#define BB 2
#define SS 2048
#define DD 1024
#define HH 16
#define DHD 64
#define FFD 4096
#define NROWS (BB*SS)

typedef __bf16 bf16_t;
typedef __bf16 bf16x8 __attribute__((ext_vector_type(8)));
typedef float floatx4 __attribute__((ext_vector_type(4)));

union FragU { uint4 u; bf16x8 v; bf16_t e[8]; };

static __device__ __forceinline__ bf16x8 ld_frag16(const bf16_t* p) {
  FragU f; f.u = *reinterpret_cast<const uint4*>(p); return f.v;
}

// async global->LDS 16B: lane i of the wave lands at lptr + i*16 (wave-uniform base!)
static __device__ __forceinline__ void gl_lds16(const bf16_t* g, bf16_t* l) {
  __builtin_amdgcn_global_load_lds(
      (const __attribute__((address_space(1))) unsigned int*)g,
      (__attribute__((address_space(3))) unsigned int*)l, 16, 0, 0);
}

// flag-dependent scalar read of a "float param" tensor (f32 or bf16)
static __device__ __forceinline__ float ld_param(const void* p, int i, int f32m) {
  return f32m ? ((const float*)p)[i] : (float)((const bf16_t*)p)[i];
}

// ---------------------------------------------------------------------------
// Detector: flags[0]=1 if float tensors are really f32; flags[1]=1 if masks int8.
// ---------------------------------------------------------------------------
__global__ __launch_bounds__(256) void detect_k(const void* __restrict__ xp,
                                                const void* __restrict__ ep,
                                                const void* __restrict__ wp,
                                                const int* __restrict__ mk,
                                                int* __restrict__ flags) {
  const int t = threadIdx.x;
  const unsigned short* a = (const unsigned short*)xp;
  const unsigned short* b = (const unsigned short*)ep;
  const unsigned short* c = (const unsigned short*)wp;
  int bad = 0, mbad = 0;
  for (int i = t; i < 4096; i += 256) {
    int e1 = (a[i] >> 7) & 0xFF, e2 = (b[i] >> 7) & 0xFF, e3 = (c[i] >> 7) & 0xFF;
    if (e1 >= 0x9B || e2 >= 0x9B || e3 >= 0x9B) bad = 1;
  }
  for (int i = t; i < 1024; i += 256) {
    unsigned v = (unsigned)mk[i];
    if (v > 1u) mbad = 1;
  }
  __shared__ int s0, s1;
  if (t == 0) { s0 = 0; s1 = 0; }
  __syncthreads();
  if (bad)  atomicOr(&s0, 1);
  if (mbad) atomicOr(&s1, 1);
  __syncthreads();
  if (t == 0) { flags[0] = s0; flags[1] = s1; }
}

// ---------------------------------------------------------------------------
// Canonicalize a float tensor to bf16 (copy if already bf16).
// ---------------------------------------------------------------------------
__global__ __launch_bounds__(256) void cvt_k(const void* __restrict__ src,
                                             bf16_t* __restrict__ dst, int n,
                                             const int* __restrict__ flg) {
  const int f32m = flg[0];
  const int idx = blockIdx.x * 256 + threadIdx.x;
  const int stride = gridDim.x * 256;
  if (f32m) {
    const float* s = (const float*)src;
    for (int i = idx; i < n; i += stride) dst[i] = (bf16_t)s[i];
  } else {
    const bf16_t* s = (const bf16_t*)src;
    for (int i = idx; i < n; i += stride) dst[i] = s[i];
  }
}

// ---------------------------------------------------------------------------
// Transpose core (shared by single & batched kernels).
// ---------------------------------------------------------------------------
static __device__ __forceinline__ void transpose_body(const void* inv, bf16_t* out,
                                                      int rows, int cols, int f32m) {
  __shared__ __align__(16) bf16_t tile[64][72];
  const int c0 = blockIdx.x * 64, r0 = blockIdx.y * 64;
  const int t  = threadIdx.x;
  const int lr = t >> 3;            // 0..31
  const int lc = (t & 7) * 8;       // 0..56
#pragma unroll
  for (int half = 0; half < 2; ++half) {
    int r = lr + half * 32;
    if (f32m) {
      const float* p = (const float*)inv + (size_t)(r0 + r) * cols + c0 + lc;
      float4 q0 = *reinterpret_cast<const float4*>(p);
      float4 q1 = *reinterpret_cast<const float4*>(p + 4);
      tile[r][lc+0] = (bf16_t)q0.x; tile[r][lc+1] = (bf16_t)q0.y;
      tile[r][lc+2] = (bf16_t)q0.z; tile[r][lc+3] = (bf16_t)q0.w;
      tile[r][lc+4] = (bf16_t)q1.x; tile[r][lc+5] = (bf16_t)q1.y;
      tile[r][lc+6] = (bf16_t)q1.z; tile[r][lc+7] = (bf16_t)q1.w;
    } else {
      uint4 vv = *reinterpret_cast<const uint4*>((const bf16_t*)inv + (size_t)(r0 + r) * cols + c0 + lc);
      *reinterpret_cast<uint4*>(&tile[r][lc]) = vv;
    }
  }
  __syncthreads();
#pragma unroll
  for (int half = 0; half < 2; ++half) {
    int oc = lr + half * 32;
    FragU f;
#pragma unroll
    for (int j = 0; j < 8; ++j) f.e[j] = tile[lc + j][oc];
    *reinterpret_cast<uint4*>(out + (size_t)(c0 + oc) * rows + r0 + lc) = f.u;
  }
}

__global__ __launch_bounds__(256) void transpose_k(const void* __restrict__ inv,
                                                   bf16_t* __restrict__ out,
                                                   int rows, int cols,
                                                   const int* __restrict__ flg) {
  transpose_body(inv, out, rows, cols, flg[0]);
}

struct Ptr4 { const void* p0; const void* p1; const void* p2; const void* p3; };

// 4 D x D transposes in one launch: grid (16,16,4)
__global__ __launch_bounds__(256) void transpose4_k(Ptr4 in, bf16_t* __restrict__ out,
                                                    const int* __restrict__ flg) {
  const void* src = (blockIdx.z == 0) ? in.p0 : (blockIdx.z == 1) ? in.p1
                   : (blockIdx.z == 2) ? in.p2 : in.p3;
  transpose_body(src, out + (size_t)blockIdx.z * DD * DD, DD, DD, flg[0]);
}

// ---------------------------------------------------------------------------
// GEMM (m97-style): C[M,N] = A[M,K] @ Bt[N,K]^T (+bias, +GELU).
// 128x128 tile, BK=32, 256 thr = 4 waves, each wave 64x64 (4x4 16x16x32 frags).
// Staging via global_load_lds width=16 into UNPADDED [128][32] LDS tiles.
// bias read f32-or-bf16 per flg[0].  grid (N/128, M/128).
// ---------------------------------------------------------------------------
template<int BIAS, int GELU>
__global__ __launch_bounds__(256) void gemm_nt(const bf16_t* __restrict__ A,
                                               const bf16_t* __restrict__ Bt,
                                               const void* __restrict__ bias,
                                               bf16_t* __restrict__ C,
                                               int M, int N, int K,
                                               const int* __restrict__ flg) {
  __shared__ __align__(16) bf16_t As[128 * 32];
  __shared__ __align__(16) bf16_t Bs[128 * 32];
  const int m0 = blockIdx.y * 128, n0 = blockIdx.x * 128;
  const int t = threadIdx.x, lane = t & 63, w = t >> 6;
  const int quad = lane >> 4, l16 = lane & 15;
  const int wy = w >> 1, wx = w & 1;

  floatx4 acc[4][4];
#pragma unroll
  for (int i = 0; i < 4; ++i)
#pragma unroll
    for (int j = 0; j < 4; ++j) { floatx4 z = {0.f,0.f,0.f,0.f}; acc[i][j] = z; }

  const int srow = lane >> 2;
  const int scol = (lane & 3) * 8;

  for (int k0 = 0; k0 < K; k0 += 32) {
    __syncthreads();
#pragma unroll
    for (int c = 0; c < 2; ++c) {
      const int chunk = w * 2 + c;
      const int r = chunk * 16 + srow;
      gl_lds16(A  + (size_t)(m0 + r) * K + k0 + scol, As + chunk * 512);
      gl_lds16(Bt + (size_t)(n0 + r) * K + k0 + scol, Bs + chunk * 512);
    }
    __syncthreads();

    bf16x8 af[4], bfr[4];
#pragma unroll
    for (int mt = 0; mt < 4; ++mt) af[mt]  = ld_frag16(As + (wy*64 + mt*16 + l16) * 32 + quad*8);
#pragma unroll
    for (int nt = 0; nt < 4; ++nt) bfr[nt] = ld_frag16(Bs + (wx*64 + nt*16 + l16) * 32 + quad*8);
#pragma unroll
    for (int mt = 0; mt < 4; ++mt)
#pragma unroll
      for (int nt = 0; nt < 4; ++nt)
        acc[mt][nt] = __builtin_amdgcn_mfma_f32_16x16x32_bf16(af[mt], bfr[nt], acc[mt][nt], 0, 0, 0);
  }

  const int f32m = BIAS ? flg[0] : 0;
#pragma unroll
  for (int nt = 0; nt < 4; ++nt) {
    const int c = n0 + wx*64 + nt*16 + l16;
    float bv = 0.f;
    if (BIAS) bv = ld_param(bias, c, f32m);
#pragma unroll
    for (int mt = 0; mt < 4; ++mt) {
      const int rb = m0 + wy*64 + mt*16 + quad*4;
#pragma unroll
      for (int reg = 0; reg < 4; ++reg) {
        float v2 = acc[mt][nt][reg] + bv;
        if (GELU) v2 = 0.5f * v2 * (1.f + erff(v2 * 0.70710678118654752f));
        C[(size_t)(rb + reg) * N + c] = (bf16_t)v2;
      }
    }
  }
}

// ---------------------------------------------------------------------------
// MFMA flash attention, 64-key tiles.  Q,K,V: [B*S,1024], head h = cols h*64..
// grid (S/64, B*H), block 256 (4 waves x 16 q-rows).
// - exp2 domain, additive mask (-1e30) preloaded to LDS: no selects/guards.
// - l_i via MFMA with ones-B (no sum shuffles).
// - Vt: chunk-XOR swizzle, staging map key=t&63 -> 2-way (free) scalar writes.
// ---------------------------------------------------------------------------
__global__ __launch_bounds__(256) void attn_k(const bf16_t* __restrict__ Q,
                                              const bf16_t* __restrict__ Kb,
                                              const bf16_t* __restrict__ Vb,
                                              const int* __restrict__ mask,
                                              bf16_t* __restrict__ O,
                                              const int* __restrict__ flg) {
  __shared__ __align__(16) bf16_t Ks[64 * 72];    // [key][dh] stride 72
  __shared__ __align__(16) bf16_t Vt[64 * 72];    // [dh][key, chunk-swizzled]
  __shared__ __align__(16) bf16_t Ps[4][16 * 72]; // per-wave P [qrow][key]
  __shared__ float msk[SS];                       // additive mask row (0 / -1e30)
  const int mflag = flg[1];
  const int b = blockIdx.y >> 4, h = blockIdx.y & 15;
  const int s0 = blockIdx.x * 64;
  const int t = threadIdx.x, w = t >> 6, lane = t & 63;
  const int quad = lane >> 4, l16 = lane & 15;
  const float L2S = 0.18033688011112042f;   // 0.125 * log2(e)

  // preload additive mask row
  for (int j = t; j < SS; j += 256) {
    const int mv = mflag ? (int)((const signed char*)mask)[b * SS + j] : mask[b * SS + j];
    msk[j] = mv ? -1.0e30f : 0.0f;
  }

  // Q A-fragments (m=l16, k=quad*8+j), 2 ksteps over DH=64
  bf16x8 qf[2];
  {
    const int r = s0 + w * 16 + l16;
    const bf16_t* qp = Q + (size_t)(b * SS + r) * DD + h * DHD;
#pragma unroll
    for (int kq = 0; kq < 2; ++kq) qf[kq] = ld_frag16(qp + kq * 32 + quad * 8);
  }

  bf16x8 ones;
#pragma unroll
  for (int j = 0; j < 8; ++j) ones[j] = (bf16_t)1.0f;

  float m_i[4];
  floatx4 accO[4], accl;
  { floatx4 z = {0.f,0.f,0.f,0.f}; accl = z;
#pragma unroll
    for (int i = 0; i < 4; ++i) { m_i[i] = -1.0e30f; accO[i] = z; } }

  // staging maps
  const int krow = t >> 2, kc = (t & 3) * 16;      // K: coalesced rows
  const int vkey = t & 63, vw16 = (t >> 6) * 16;   // V: bank-friendly transpose
  const int vq = vkey >> 3, vk7 = vkey & 7;
  const int vs0 = (vw16 >> 3) & 7, vs1 = (vs0 + 1) & 7;

  for (int j0 = 0; j0 < SS; j0 += 64) {
    __syncthreads();                 // prev-iter Ks/Vt/Ps reads done
    {
      const bf16_t* kp = Kb + (size_t)(b * SS + j0 + krow) * DD + h * DHD + kc;
      uint4 k0 = *reinterpret_cast<const uint4*>(kp);
      uint4 k1 = *reinterpret_cast<const uint4*>(kp + 8);
      *reinterpret_cast<uint4*>(&Ks[krow * 72 + kc])     = k0;
      *reinterpret_cast<uint4*>(&Ks[krow * 72 + kc + 8]) = k1;
      const bf16_t* vp = Vb + (size_t)(b * SS + j0 + vkey) * DD + h * DHD + vw16;
      FragU v0; v0.u = *reinterpret_cast<const uint4*>(vp);
      FragU v1; v1.u = *reinterpret_cast<const uint4*>(vp + 8);
#pragma unroll
      for (int j = 0; j < 8; ++j) Vt[(vw16 + j) * 72 + ((vq ^ vs0) << 3) + vk7] = v0.e[j];
#pragma unroll
      for (int j = 0; j < 8; ++j) Vt[(vw16 + 8 + j) * 72 + ((vq ^ vs1) << 3) + vk7] = v1.e[j];
    }
    __syncthreads();

    // S = Q K^T : 4 col-frags (keys cf*16+l16) x 2 ksteps
    floatx4 s4[4];
    { floatx4 z = {0.f,0.f,0.f,0.f};
#pragma unroll
      for (int cf = 0; cf < 4; ++cf) s4[cf] = z; }
#pragma unroll
    for (int kq = 0; kq < 2; ++kq)
#pragma unroll
      for (int cf = 0; cf < 4; ++cf) {
        bf16x8 bf = ld_frag16(&Ks[(cf * 16 + l16) * 72 + kq * 32 + quad * 8]);
        s4[cf] = __builtin_amdgcn_mfma_f32_16x16x32_bf16(qf[kq], bf, s4[cf], 0, 0, 0);
      }
    float ml[4];
#pragma unroll
    for (int cf = 0; cf < 4; ++cf) ml[cf] = msk[j0 + cf * 16 + l16];

    // online softmax (exp2 domain), per q-row = quad*4+reg
    floatx4 av;
#pragma unroll
    for (int reg = 0; reg < 4; ++reg) {
      float f0 = s4[0][reg] * L2S + ml[0];
      float f1 = s4[1][reg] * L2S + ml[1];
      float f2 = s4[2][reg] * L2S + ml[2];
      float f3 = s4[3][reg] * L2S + ml[3];
      float mx = fmaxf(fmaxf(f0, f1), fmaxf(f2, f3));
#pragma unroll
      for (int off = 1; off < 16; off <<= 1) mx = fmaxf(mx, __shfl_xor(mx, off, 64));
      const float mn = fmaxf(m_i[reg], mx);
      av[reg] = exp2f(m_i[reg] - mn);
      m_i[reg] = mn;
      const int rb = (quad * 4 + reg) * 72;
      Ps[w][rb + l16]      = (bf16_t)exp2f(f0 - mn);
      Ps[w][rb + 16 + l16] = (bf16_t)exp2f(f1 - mn);
      Ps[w][rb + 32 + l16] = (bf16_t)exp2f(f2 - mn);
      Ps[w][rb + 48 + l16] = (bf16_t)exp2f(f3 - mn);
    }
#pragma unroll
    for (int nt = 0; nt < 4; ++nt) accO[nt] *= av;
    accl *= av;
    __syncthreads();                 // Ps cross-lane write -> read

    // O += P V ; l += P 1
    bf16x8 pa0 = ld_frag16(&Ps[w][l16 * 72 + quad * 8]);
    bf16x8 pa1 = ld_frag16(&Ps[w][l16 * 72 + 32 + quad * 8]);
#pragma unroll
    for (int nt = 0; nt < 4; ++nt) {
      const int dh = nt * 16 + l16;
      const int sdh = (dh >> 3) & 7;
      bf16x8 vf0 = ld_frag16(&Vt[dh * 72 + ((quad ^ sdh) << 3)]);
      bf16x8 vf1 = ld_frag16(&Vt[dh * 72 + (((4 + quad) ^ sdh) << 3)]);
      accO[nt] = __builtin_amdgcn_mfma_f32_16x16x32_bf16(pa0, vf0, accO[nt], 0, 0, 0);
      accO[nt] = __builtin_amdgcn_mfma_f32_16x16x32_bf16(pa1, vf1, accO[nt], 0, 0, 0);
    }
    accl = __builtin_amdgcn_mfma_f32_16x16x32_bf16(pa0, ones, accl, 0, 0, 0);
    accl = __builtin_amdgcn_mfma_f32_16x16x32_bf16(pa1, ones, accl, 0, 0, 0);
  }

#pragma unroll
  for (int nt = 0; nt < 4; ++nt)
#pragma unroll
    for (int reg = 0; reg < 4; ++reg) {
      const int r = s0 + w * 16 + quad * 4 + reg;
      const int c = h * DHD + nt * 16 + l16;
      O[(size_t)(b * SS + r) * DD + c] = (bf16_t)(accO[nt][reg] / accl[reg]);
    }
}

// ---------------------------------------------------------------------------
// y = LayerNorm(x + a) * g + b.  One block per row.  Alias-safe (Y==X ok).
// g/bb read f32-or-bf16 per flg[0]; final_out!=0 writes f32 if flg[0].
// ---------------------------------------------------------------------------
__global__ __launch_bounds__(256) void ln_add_k(const bf16_t* __restrict__ X,
                                                const bf16_t* __restrict__ A,
                                                const void* __restrict__ g,
                                                const void* __restrict__ bb,
                                                void* __restrict__ Yv,
                                                const int* __restrict__ flg,
                                                int final_out) {
  const int row = blockIdx.x;
  const int t = threadIdx.x;
  const int f32m = flg[0];
  const int f32o = final_out ? f32m : 0;
  const bf16_t* xp = X + (size_t)row * DD;
  const bf16_t* ap = A + (size_t)row * DD;
  float v[4], s = 0.f, sq = 0.f;
#pragma unroll
  for (int i = 0; i < 4; ++i) {
    float xv = (float)xp[t + i * 256] + (float)ap[t + i * 256];
    v[i] = xv; s += xv; sq += xv * xv;
  }
#pragma unroll
  for (int off = 1; off < 64; off <<= 1) {
    s  += __shfl_xor(s, off, 64);
    sq += __shfl_xor(sq, off, 64);
  }
  __shared__ float red[2][4];
  const int w = t >> 6, lane = t & 63;
  if (lane == 0) { red[0][w] = s; red[1][w] = sq; }
  __syncthreads();
  s  = red[0][0] + red[0][1] + red[0][2] + red[0][3];
  sq = red[1][0] + red[1][1] + red[1][2] + red[1][3];
  const float mean = s * (1.f / 1024.f);
  const float var  = sq * (1.f / 1024.f) - mean * mean;
  const float rstd = rsqrtf(var + 1e-5f);
#pragma unroll
  for (int i = 0; i < 4; ++i) {
    const int c = t + i * 256;
    const float val = (v[i] - mean) * rstd * ld_param(g, c, f32m) + ld_param(bb, c, f32m);
    if (f32o) ((float*)Yv)[(size_t)row * DD + c] = val;
    else      ((bf16_t*)Yv)[(size_t)row * DD + c] = (bf16_t)val;
  }
}

// ---------------------------------------------------------------------------
__global__ __launch_bounds__(256) void beacon_k(bf16_t* out, int n, float val) {
  int i = blockIdx.x * 256 + threadIdx.x;
  if (i < n) out[i] = (bf16_t)val;
}

// ---------------------------------------------------------------------------
extern "C" void kernel_launch(void* const* d_in, const int* in_sizes, int n_in,
                              void* d_out, int out_size, void* d_ws, size_t ws_size,
                              hipStream_t stream) {
  const dim3 blk(256);
  const dim3 gB((out_size + 255) / 256);

  static const int expect[24] = {
    4194304, 4194304,
    1048576, 1048576, 1048576, 1048576, 1024,
    1048576, 1048576, 1048576, 1048576, 1024,
    1024, 1024, 1024, 1024, 1024, 1024,
    4194304, 4096,
    4194304, 1024,
    4096, 4096
  };
  if (n_in != 24) {
    beacon_k<<<gB, blk, 0, stream>>>((bf16_t*)d_out, out_size, 200.f + (float)(n_in & 63));
    return;
  }
  for (int i = 0; i < 24; ++i) {
    if (in_sizes[i] != expect[i]) {
      beacon_k<<<gB, blk, 0, stream>>>((bf16_t*)d_out, out_size, 20.f + 2.f * (float)i);
      return;
    }
  }

  const void* x_raw   = d_in[0];
  const void* enc_raw = d_in[1];
  const void* sa_wq = d_in[2], *sa_wk = d_in[3], *sa_wv = d_in[4], *sa_wo = d_in[5];
  const void* sa_bo = d_in[6];
  const void* ca_wq = d_in[7], *ca_wk = d_in[8], *ca_wv = d_in[9], *ca_wo = d_in[10];
  const void* ca_bo = d_in[11];
  const void* ln1_g = d_in[12], *ln1_b = d_in[13];
  const void* ln2_g = d_in[14], *ln2_b = d_in[15];
  const void* ln3_g = d_in[16], *ln3_b = d_in[17];
  const void* fc1_w = d_in[18], *fc1_b = d_in[19];
  const void* fc2_w = d_in[20], *fc2_b = d_in[21];
  const int* tgt_mask = (const int*)d_in[22];
  const int* src_mask = (const int*)d_in[23];

  const size_t SEG = (size_t)NROWS * DD;           // 4,194,304 elems = 8 MiB bf16
  const size_t PS_ELEMS = 32768;
  if (ws_size < (8 * SEG + PS_ELEMS) * sizeof(bf16_t)) {
    beacon_k<<<gB, blk, 0, stream>>>((bf16_t*)d_out, out_size, 7.f);
    return;
  }
  bf16_t* ws = (bf16_t*)d_ws;
  bf16_t* qb = ws + 0 * SEG;        // q / attn-out t0
  bf16_t* kb = ws + 1 * SEG;
  bf16_t* vb = ws + 2 * SEG;        // v / MLP h-chunk (chunked path)
  bf16_t* wt = ws + 3 * SEG;        // 4 transposed DxD weights per phase / fc1^T / fc2^T
  bf16_t* t1 = ws + 4 * SEG;
  bf16_t* x1 = ws + 5 * SEG;        // ln1 out; ln2 in-place out (x2)
  bf16_t* xc = ws + 6 * SEG;        // canonical bf16 x
  bf16_t* ec = ws + 7 * SEG;        // canonical bf16 enc
  bf16_t* ps = ws + 8 * SEG;
  int*    fl = (int*)(ps + 16384);  // flags
  bf16_t* t0 = qb;
  bf16_t* x2 = x1;
  const bool big_ws = ws_size >= (12 * SEG + PS_ELEMS) * sizeof(bf16_t);
  bf16_t* hb = ws + 8 * SEG + PS_ELEMS;

  const size_t W1 = (size_t)DD * DD;   // 1M elems per transposed DxD weight
  bf16_t* wqt = wt + 0 * W1;
  bf16_t* wkt = wt + 1 * W1;
  bf16_t* wvt = wt + 2 * W1;
  bf16_t* wot = wt + 3 * W1;

  const dim3 gT4(16, 16, 4);
  const dim3 gG(DD / 128, NROWS / 128);
  const dim3 gA(SS / 64, BB * HH);
  const dim3 gL(NROWS);
  const dim3 gC(512);

  // ---- detect dtypes, canonicalize activations ----
  detect_k<<<dim3(1), blk, 0, stream>>>(x_raw, enc_raw, fc1_w, tgt_mask, fl);
  cvt_k<<<gC, blk, 0, stream>>>(x_raw,   xc, (int)SEG, fl);
  cvt_k<<<gC, blk, 0, stream>>>(enc_raw, ec, (int)SEG, fl);

  // ---- self attention ----
  { Ptr4 p{sa_wq, sa_wk, sa_wv, sa_wo};
    transpose4_k<<<gT4, blk, 0, stream>>>(p, wt, fl); }
  gemm_nt<0,0><<<gG, blk, 0, stream>>>(xc, wqt, nullptr, qb, NROWS, DD, DD, fl);
  gemm_nt<0,0><<<gG, blk, 0, stream>>>(xc, wkt, nullptr, kb, NROWS, DD, DD, fl);
  gemm_nt<0,0><<<gG, blk, 0, stream>>>(xc, wvt, nullptr, vb, NROWS, DD, DD, fl);
  attn_k<<<gA, blk, 0, stream>>>(qb, kb, vb, tgt_mask, t0, fl);
  gemm_nt<1,0><<<gG, blk, 0, stream>>>(t0, wot, sa_bo, t1, NROWS, DD, DD, fl);
  ln_add_k<<<gL, blk, 0, stream>>>(xc, t1, ln1_g, ln1_b, x1, fl, 0);

  // ---- cross attention ----
  { Ptr4 p{ca_wq, ca_wk, ca_wv, ca_wo};
    transpose4_k<<<gT4, blk, 0, stream>>>(p, wt, fl); }
  gemm_nt<0,0><<<gG, blk, 0, stream>>>(x1, wqt, nullptr, qb, NROWS, DD, DD, fl);
  gemm_nt<0,0><<<gG, blk, 0, stream>>>(ec, wkt, nullptr, kb, NROWS, DD, DD, fl);
  gemm_nt<0,0><<<gG, blk, 0, stream>>>(ec, wvt, nullptr, vb, NROWS, DD, DD, fl);
  attn_k<<<gA, blk, 0, stream>>>(qb, kb, vb, src_mask, t0, fl);
  gemm_nt<1,0><<<gG, blk, 0, stream>>>(t0, wot, ca_bo, t1, NROWS, DD, DD, fl);
  ln_add_k<<<gL, blk, 0, stream>>>(x1, t1, ln2_g, ln2_b, x2, fl, 0);

  // ---- MLP ----
  transpose_k<<<dim3(FFD/64, DD/64), blk, 0, stream>>>(fc1_w, wt, DD, FFD, fl);  // fc1^T
  if (big_ws) {
    gemm_nt<1,1><<<dim3(FFD/128, NROWS/128), blk, 0, stream>>>(x2, wt, fc1_b, hb, NROWS, FFD, DD, fl);
    transpose_k<<<dim3(DD/64, FFD/64), blk, 0, stream>>>(fc2_w, wt, FFD, DD, fl); // fc2^T
    gemm_nt<1,0><<<dim3(DD/128,  NROWS/128), blk, 0, stream>>>(hb, wt, fc2_b, t1, NROWS, DD, FFD, fl);
  } else {
    transpose_k<<<dim3(DD/64, FFD/64), blk, 0, stream>>>(fc2_w, kb, FFD, DD, fl); // fc2^T in kb
    for (int c = 0; c < 4; ++c) {
      gemm_nt<1,1><<<dim3(FFD/128, 8), blk, 0, stream>>>(x2 + (size_t)c*1024*DD, wt, fc1_b, vb, 1024, FFD, DD, fl);
      gemm_nt<1,0><<<dim3(DD/128,  8), blk, 0, stream>>>(vb, kb, fc2_b, t1 + (size_t)c*1024*DD, 1024, DD, FFD, fl);
    }
  }
  ln_add_k<<<gL, blk, 0, stream>>>(x2, t1, ln3_g, ln3_b, d_out, fl, 1);
}